// Round 9
// baseline (852.585 us; speedup 1.0000x reference)
//
#include <hip/hip_runtime.h>
#include <hip/hip_bf16.h>
#include <stdint.h>
#include <stddef.h>

#define BB 2
#define NN 384
#define DD 768
#define HH 256
#define SS 64
#define NHH 8
#define DHH 96

typedef __attribute__((ext_vector_type(8))) short bf16x8;
typedef __attribute__((ext_vector_type(4))) float f32x4;

__device__ __forceinline__ float bits_f(unsigned short u){
  unsigned x = ((unsigned)u) << 16; float f; __builtin_memcpy(&f, &x, 4); return f;
}
__device__ __forceinline__ unsigned short f_bits(float a){
  unsigned x; __builtin_memcpy(&x, &a, 4);
  unsigned r = x + 0x7fffu + ((x >> 16) & 1u);
  return (unsigned short)(r >> 16);
}
__device__ __forceinline__ float lo_f(unsigned u){ unsigned x = u << 16; float f; __builtin_memcpy(&f,&x,4); return f; }
__device__ __forceinline__ float hi_f(unsigned u){ unsigned x = u & 0xffff0000u; float f; __builtin_memcpy(&f,&x,4); return f; }

// ================= prep: zeroing + all transposes (LDS-tiled, coalesced) =================
__global__ __launch_bounds__(256) void k_prep(
    const float* __restrict__ w2, const float* __restrict__ w1g,
    const float* __restrict__ wq, const float* __restrict__ wk,
    const float* __restrict__ wv, const float* __restrict__ wo,
    float* __restrict__ zf, short* __restrict__ w2T, short* __restrict__ w2r,
    short* __restrict__ wqT, short* __restrict__ wkT, short* __restrict__ wvT,
    short* __restrict__ woT, short* __restrict__ w1t)
{
  __shared__ short tile[64*66];
  const int tid = threadIdx.x, blk = blockIdx.x;
  if (blk < 1549){
    int idx = blk*256 + tid;
    if (idx < 396416) zf[idx] = 0.f;
    return;
  }
  if (blk < 1597){            // w2 [256,768] -> w2T [768,256]
    int t = blk - 1549;
    int r0 = (t/12)*64, c0 = (t%12)*64;
    int g = tid >> 6, c = tid & 63;
    #pragma unroll
    for (int i=0;i<16;++i){
      int r = i*4 + g;
      tile[r*66 + c] = (short)f_bits(w2[(size_t)(r0+r)*768 + c0 + c]);
    }
    __syncthreads();
    #pragma unroll
    for (int i=0;i<16;++i){
      int cc = i*4 + g, rr = c;
      w2T[(size_t)(c0+cc)*256 + r0 + rr] = tile[rr*66 + cc];
    }
    return;
  }
  if (blk < 2365){            // w2r: row-major bf16 copy
    int idx = (blk-1597)*256 + tid;
    w2r[idx] = (short)f_bits(w2[idx]);
    return;
  }
  if (blk < 2941){            // attn weights [768,768] -> T[n][k]
    int t = blk - 2365;
    int mat = t / 144, tt = t % 144;
    const float* W = (mat==0)?wq:(mat==1)?wk:(mat==2)?wv:wo;
    short* T = (mat==0)?wqT:(mat==1)?wkT:(mat==2)?wvT:woT;
    int r0 = (tt/12)*64, c0 = (tt%12)*64;
    int g = tid >> 6, c = tid & 63;
    #pragma unroll
    for (int i=0;i<16;++i){
      int r = i*4 + g;
      tile[r*66 + c] = (short)f_bits(W[(size_t)(r0+r)*768 + c0 + c]);
    }
    __syncthreads();
    #pragma unroll
    for (int i=0;i<16;++i){
      int cc = i*4 + g, rr = c;
      T[(size_t)(c0+cc)*768 + r0 + rr] = tile[rr*66 + cc];
    }
    return;
  }
  {                           // w1t [256c][32k], K padded
    int idx = (blk-2941)*256 + tid;
    int c = idx >> 5, kk = idx & 31;
    w1t[idx] = (kk < 9) ? (short)f_bits(w1g[kk*256 + c]) : (short)0;
  }
}

// ================= Gram prep: Gm[288][256] (rows 256=s1,257=wb,258+=0), gscal, w1 stats =================
__global__ __launch_bounds__(256) void k_gprep(const short* __restrict__ w2T,
                                               const float* __restrict__ b2,
                                               const short* __restrict__ w1t,
                                               const float* __restrict__ b1,
                                               short* __restrict__ Gm, float* __restrict__ gscal,
                                               float* __restrict__ g1s){
  __shared__ float red[8];
  const int tid = threadIdx.x, blk = blockIdx.x;
  const unsigned short* wt = (const unsigned short*)w2T;
  if (blk < 256){
    float acc = 0.f;
    for (int c = 0; c < 768; ++c){
      float a = bits_f(wt[c*256 + blk]);
      float x = bits_f(wt[c*256 + tid]);
      acc += a * x;
    }
    Gm[blk*256 + tid] = (short)f_bits(acc);
  } else if (blk == 256){
    float sa = 0.f, wa = 0.f;
    for (int c = 0; c < 768; ++c){
      float x = bits_f(wt[c*256 + tid]);
      float bb = b2[c];
      sa += x; wa += x * bb;
    }
    Gm[256*256 + tid] = (short)f_bits(sa);
    Gm[257*256 + tid] = (short)f_bits(wa);
    #pragma unroll
    for (int rr = 258; rr < 288; ++rr) Gm[rr*256 + tid] = 0;
    float pb = 0.f, pbb = 0.f;
    for (int c = tid; c < 768; c += 256){ float bb = b2[c]; pb += bb; pbb += bb*bb; }
    for (int m = 32; m >= 1; m >>= 1){ pb += __shfl_xor(pb,m); pbb += __shfl_xor(pbb,m); }
    if ((tid & 63) == 0){ red[tid>>6] = pb; red[4+(tid>>6)] = pbb; }
    __syncthreads();
    if (tid == 0){ gscal[0] = red[0]+red[1]+red[2]+red[3]; gscal[1] = red[4]+red[5]+red[6]+red[7]; }
  } else {
    // g1s[0..8]=s1a, [9..17]=w1b1, [18..98]=G1(9x9), [99]=Sb1, [100]=Sb1b
    const unsigned short* w1u = (const unsigned short*)w1t;
    if (tid < 81){
      int i = tid / 9, j = tid % 9;
      float acc = 0.f;
      for (int c = 0; c < 256; ++c)
        acc += bits_f(w1u[c*32 + i]) * bits_f(w1u[c*32 + j]);
      g1s[18 + tid] = acc;
    } else if (tid < 90){
      int i = tid - 81;
      float sa = 0.f, sb = 0.f;
      for (int c = 0; c < 256; ++c){
        float x = bits_f(w1u[c*32 + i]);
        sa += x; sb += x * b1[c];
      }
      g1s[i] = sa; g1s[9 + i] = sb;
    } else if (tid == 90){
      float pb = 0.f, pbb = 0.f;
      for (int c = 0; c < 256; ++c){ float bb = b1[c]; pb += bb; pbb += bb*bb; }
      g1s[99] = pb; g1s[100] = pbb;
    }
  }
}

// ================= geometric encoder; WG=(pair,jt), 256 thr, 4 waves =================
// Chunked phases (2 col-tiles per chunk) keep live regs < 128 -> no scratch spill at 4 WG/CU.
__global__ __launch_bounds__(256, 4) void k_geo(
    const float* __restrict__ coord, const short* __restrict__ w1t,
    const float* __restrict__ b1g, const float* __restrict__ g1g, const float* __restrict__ be1g,
    const short* __restrict__ Gm, const float* __restrict__ gscal,
    const float* __restrict__ g1s, float* __restrict__ gv)
{
  __shared__ short relbf[64*36];
  __shared__ short h_bf[64*256];   // chunk-swizzled: phys_chunk=((col>>3)+row)&31
  __shared__ float rmean[64], rrstd[64];
  __shared__ float msum[64], wbsum[64], qsum[64];

  const int tid = threadIdx.x;
  const int pair = blockIdx.x % 768;
  const int jt   = blockIdx.x / 768;
  const int j0 = jt * 64;
  const int b = pair / NN;

  // ---- phase 1: rel rows + exact LN1 stats via 9x9 Gram
  if (tid < 64){
    int j = j0 + tid;
    float cix = coord[pair*3+0], ciy = coord[pair*3+1], ciz = coord[pair*3+2];
    float dx = cix - coord[(b*NN+j)*3+0];
    float dy = ciy - coord[(b*NN+j)*3+1];
    float dz = ciz - coord[(b*NN+j)*3+2];
    float dist = sqrtf(dx*dx + dy*dy + dz*dz);
    float inv = 1.f / fmaxf(dist, 1e-12f);
    float x = dx*inv, y = dy*inv, z = dz*inv;
    float rv[9];
    rv[0]=dist; rv[1]=x; rv[2]=y; rv[3]=z; rv[4]=0.f; rv[5]=0.f;
    rv[6]=y*z; rv[7]=x*y; rv[8]=x*z;
    short* rr = &relbf[tid*36];
    float rbf[9];
    #pragma unroll
    for (int k=0;k<9;++k){
      unsigned short hb = f_bits(rv[k]);
      rr[k] = (short)hb; rbf[k] = bits_f(hb);
    }
    #pragma unroll
    for (int k=9;k<32;++k) rr[k]=0;
    float s = g1s[99], ssq = g1s[100];
    #pragma unroll
    for (int i=0;i<9;++i){
      s += rbf[i]*g1s[i];
      ssq += 2.f*rbf[i]*g1s[9+i];
      #pragma unroll
      for (int jj=0;jj<9;++jj) ssq += rbf[i]*rbf[jj]*g1s[18+i*9+jj];
    }
    float mean = s*(1.f/256.f);
    float var  = ssq*(1.f/256.f) - mean*mean;
    rmean[tid] = mean; rrstd[tid] = rsqrtf(var + 1e-5f);
  } else if (tid < 128){
    qsum[tid-64] = 0.f;
  }
  __syncthreads();

  const int wave = tid >> 6, lane = tid & 63, quad = lane >> 4, l16 = lane & 15;

  // ---- phase 2: MFMA mm1 + in-register LN1/ReLU -> h_bf (chunked: 2 col-tiles at a time)
  {
    bf16x8 af[4];
    #pragma unroll
    for (int rb=0;rb<4;++rb)
      af[rb] = *(const bf16x8*)&relbf[(rb*16 + l16)*36 + quad*8];
    f32x4 rmv[4], rsv[4];
    #pragma unroll
    for (int rb=0;rb<4;++rb){
      rmv[rb] = *(const f32x4*)&rmean[rb*16 + quad*4];
      rsv[rb] = *(const f32x4*)&rrstd[rb*16 + quad*4];
    }
    #pragma unroll 1
    for (int hc = 0; hc < 2; ++hc){
      f32x4 hacc[2][4];
      #pragma unroll
      for (int ci=0;ci<2;++ci){
        int cb = wave*4 + hc*2 + ci;
        bf16x8 bfw = *(const bf16x8*)&w1t[(cb*16 + l16)*32 + quad*8];
        #pragma unroll
        for (int rb=0;rb<4;++rb)
          hacc[ci][rb] = __builtin_amdgcn_mfma_f32_16x16x32_bf16(af[rb], bfw, (f32x4){0.f,0.f,0.f,0.f}, 0,0,0);
      }
      #pragma unroll
      for (int ci=0;ci<2;++ci){
        int col = (wave*4 + hc*2 + ci)*16 + l16;
        float b1c = b1g[col], g1c = g1g[col], be1c = be1g[col];
        int chb = col >> 3, lo = col & 7;
        #pragma unroll
        for (int rb=0;rb<4;++rb){
          #pragma unroll
          for (int r=0;r<4;++r){
            int row = rb*16 + quad*4 + r;
            float hn = (hacc[ci][rb][r] + b1c - rmv[rb][r]) * rsv[rb][r] * g1c + be1c;
            h_bf[row*256 + ((chb + row)&31)*8 + lo] = (short)f_bits(fmaxf(hn, 0.f));
          }
        }
      }
    }
  }
  __syncthreads();

  // ---- phase 3: U = H@Gm_ext (chunked); wave0 ext tile -> msum/wbsum; Q_j = sum U.h
  #pragma unroll 1
  for (int hc = 0; hc < 2; ++hc){
    f32x4 acc[2][4];
    #pragma unroll
    for (int ci=0;ci<2;++ci)
      #pragma unroll
      for (int rb=0;rb<4;++rb) acc[ci][rb] = (f32x4){0.f,0.f,0.f,0.f};
    f32x4 eacc[4];
    #pragma unroll
    for (int rb=0;rb<4;++rb) eacc[rb] = (f32x4){0.f,0.f,0.f,0.f};
    for (int ks=0;ks<8;++ks){
      bf16x8 a4[4];
      #pragma unroll
      for (int rb=0;rb<4;++rb){
        int row = rb*16 + l16;
        a4[rb] = *(const bf16x8*)&h_bf[row*256 + (((ks*4 + quad) + row)&31)*8];
      }
      #pragma unroll
      for (int ci=0;ci<2;++ci){
        int n = (wave*4 + hc*2 + ci)*16 + l16;
        bf16x8 bg = *(const bf16x8*)&Gm[n*256 + ks*32 + quad*8];
        #pragma unroll
        for (int rb=0;rb<4;++rb)
          acc[ci][rb] = __builtin_amdgcn_mfma_f32_16x16x32_bf16(a4[rb], bg, acc[ci][rb], 0,0,0);
      }
      if (hc == 0 && wave == 0){
        bf16x8 bge = *(const bf16x8*)&Gm[(256 + l16)*256 + ks*32 + quad*8];
        #pragma unroll
        for (int rb=0;rb<4;++rb)
          eacc[rb] = __builtin_amdgcn_mfma_f32_16x16x32_bf16(a4[rb], bge, eacc[rb], 0,0,0);
      }
    }
    if (hc == 0 && wave == 0 && l16 < 2){
      float* dst = (l16 == 0) ? msum : wbsum;
      #pragma unroll
      for (int rb=0;rb<4;++rb)
        #pragma unroll
        for (int r=0;r<4;++r) dst[rb*16 + quad*4 + r] = eacc[rb][r];
    }
    #pragma unroll
    for (int rb=0;rb<4;++rb){
      #pragma unroll
      for (int r=0;r<4;++r){
        int row = rb*16 + quad*4 + r;
        float qp = 0.f;
        #pragma unroll
        for (int ci=0;ci<2;++ci){
          int col = (wave*4 + hc*2 + ci)*16 + l16;
          float hv = bits_f((unsigned short)h_bf[row*256 + (((col>>3)+row)&31)*8 + (col&7)]);
          qp += acc[ci][rb][r] * hv;
        }
        qp += __shfl_xor(qp,1);
        qp += __shfl_xor(qp,2);
        qp += __shfl_xor(qp,4);
        qp += __shfl_xor(qp,8);
        if (l16 == 0) atomicAdd(&qsum[row], qp);
      }
    }
  }
  __syncthreads();
  if (tid < 64){
    float Sb = gscal[0], Sbb = gscal[1];
    float m2 = (msum[tid] + Sb)*(1.f/768.f);
    float ssq = qsum[tid] + 2.f*wbsum[tid] + Sbb;
    float var = ssq*(1.f/768.f) - m2*m2;
    rmean[tid] = m2; rrstd[tid] = rsqrtf(var + 1e-5f);
  }
  __syncthreads();
  if (tid < 64){
    float rr = rrstd[tid], tt = rmean[tid]*rrstd[tid];
    for (int m = 32; m >= 1; m >>= 1){ rr += __shfl_xor(rr,m); tt += __shfl_xor(tt,m); }
    if (tid == 0){
      atomicAdd(&gv[pair*260 + 256], rr);
      atomicAdd(&gv[pair*260 + 257], tt);
    }
  }
  {
    int col = tid, chb = col >> 3, lo = col & 7;
    float v = 0.f;
    #pragma unroll 8
    for (int j = 0; j < 64; ++j)
      v += rrstd[j] * bits_f((unsigned short)h_bf[j*256 + ((chb + j)&31)*8 + lo]);
    atomicAdd(&gv[pair*260 + col], v);
  }
}

// ================= finalize geo (coalesced w2r reads) =================
__global__ __launch_bounds__(256) void k_geofin(
    const float* __restrict__ gv, const short* __restrict__ w2r,
    const float* __restrict__ b2g, const float* __restrict__ g2g,
    const float* __restrict__ be2g, unsigned short* __restrict__ geo){
  __shared__ float V[256];
  __shared__ float RT[2];
  const int tid = threadIdx.x, pair = blockIdx.x;
  V[tid] = gv[pair*260 + tid];
  if (tid < 2) RT[tid] = gv[pair*260 + 256 + tid];
  __syncthreads();
  float R = RT[0], T = RT[1];
  const unsigned short* wr = (const unsigned short*)w2r;
  float a0 = 0.f, a1 = 0.f, a2 = 0.f;
  #pragma unroll 4
  for (int k = 0; k < 256; ++k){
    float vk = V[k];
    const unsigned short* row = wr + (size_t)k*768;
    a0 += vk * bits_f(row[tid]);
    a1 += vk * bits_f(row[tid+256]);
    a2 += vk * bits_f(row[tid+512]);
  }
  size_t base = (size_t)pair*DD;
  geo[base + tid]       = f_bits(g2g[tid]    *(a0 + b2g[tid]    *R - T)*(1.f/384.f) + be2g[tid]);
  geo[base + tid + 256] = f_bits(g2g[tid+256]*(a1 + b2g[tid+256]*R - T)*(1.f/384.f) + be2g[tid+256]);
  geo[base + tid + 512] = f_bits(g2g[tid+512]*(a2 + b2g[tid+512]*R - T)*(1.f/384.f) + be2g[tid+512]);
}

// ================= per-point scatter (atomics) =================
__global__ __launch_bounds__(256) void k_scat(
    const int* __restrict__ lab, const float* __restrict__ feat,
    const unsigned short* __restrict__ geo,
    float* __restrict__ mf, float* __restrict__ mg, float* __restrict__ cntw)
{
  const int tid = threadIdx.x, bn = blockIdx.x;
  const int b = bn / NN;
  const int s = lab[bn];
  const size_t base = (size_t)(b*SS + s)*DD;
  if (tid == 0) atomicAdd(&cntw[b*SS + s], 1.0f);
  #pragma unroll
  for (int u = 0; u < 3; ++u){
    int c = tid + 256*u;
    atomicAdd(&mf[base + c], feat[(size_t)bn*DD + c]);
    atomicAdd(&mg[base + c], bits_f(geo[(size_t)bn*DD + c]));
  }
}

// ================= aggregator MLP + combine =================
__global__ __launch_bounds__(256) void k_agg(
    const float* __restrict__ mf, const float* __restrict__ mg,
    const float* __restrict__ cntw,
    const float* __restrict__ w1g, const float* __restrict__ b1g,
    const float* __restrict__ g1g, const float* __restrict__ be1g,
    const float* __restrict__ w2g, const float* __restrict__ b2g,
    const float* __restrict__ g2g, const float* __restrict__ be2g,
    float* __restrict__ comb)
{
  __shared__ float xr[DD];
  __shared__ float hr[HH];
  __shared__ float red[8];
  const int tid = threadIdx.x;
  const size_t base = (size_t)blockIdx.x * DD;
  const float inv = 1.f / fmaxf(cntw[blockIdx.x], 1.f);
  for (int c = tid; c < DD; c += 256) xr[c] = mf[base + c]*inv;
  __syncthreads();
  float a = b1g[tid];
  #pragma unroll 4
  for (int k = 0; k < DD; ++k) a += xr[k]*w1g[k*HH + tid];
  float s = a, q = a*a;
  for (int m = 32; m >= 1; m >>= 1){ s += __shfl_xor(s,m); q += __shfl_xor(q,m); }
  if ((tid & 63) == 0){ red[tid>>6] = s; red[4+(tid>>6)] = q; }
  __syncthreads();
  s = red[0]+red[1]+red[2]+red[3]; q = red[4]+red[5]+red[6]+red[7];
  float mean = s*(1.f/HH), var = q*(1.f/HH) - mean*mean, rstd = rsqrtf(var + 1e-5f);
  float h = fmaxf((a-mean)*rstd*g1g[tid] + be1g[tid], 0.f);
  hr[tid] = h;
  __syncthreads();
  float a2[3];
  #pragma unroll
  for (int u = 0; u < 3; ++u){
    int c = tid + 256*u;
    float t = b2g[c];
    #pragma unroll 4
    for (int k = 0; k < HH; ++k) t += hr[k]*w2g[k*DD + c];
    a2[u] = t;
  }
  float s2 = a2[0]+a2[1]+a2[2], q2 = a2[0]*a2[0]+a2[1]*a2[1]+a2[2]*a2[2];
  for (int m = 32; m >= 1; m >>= 1){ s2 += __shfl_xor(s2,m); q2 += __shfl_xor(q2,m); }
  __syncthreads();
  if ((tid & 63) == 0){ red[tid>>6] = s2; red[4+(tid>>6)] = q2; }
  __syncthreads();
  s2 = red[0]+red[1]+red[2]+red[3]; q2 = red[4]+red[5]+red[6]+red[7];
  float mean2 = s2*(1.f/DD), rstd2 = rsqrtf(q2*(1.f/DD) - mean2*mean2 + 1e-5f);
  #pragma unroll
  for (int u = 0; u < 3; ++u){
    int c = tid + 256*u;
    comb[base + c] = (a2[u]-mean2)*rstd2*g2g[c] + be2g[c] + mg[base + c]*inv;
  }
}

// ================= gather + enhanced (fp32 + bf16 out) =================
__global__ void k_enhance(const float* __restrict__ feat, const int* __restrict__ lab,
                          const float* __restrict__ cntw, const float* __restrict__ comb,
                          float* __restrict__ enh, unsigned short* __restrict__ enhb)
{
  int idx = blockIdx.x * 256 + threadIdx.x;
  int c = idx % DD; int bn = idx / DD; int b = bn / NN;
  int l = lab[bn];
  float f = feat[idx];
  float cg = comb[(size_t)(b*SS + l)*DD + c];
  float cnt = cntw[b*SS + l];
  float e = (cnt >= 2.0f) ? (0.7f*f + 0.3f*cg) : f;
  enh[idx] = e;
  enhb[idx] = f_bits(e);
}

// ================= q/k/v projections via MFMA =================
__global__ __launch_bounds__(256, 4) void k_qkv(
    const unsigned short* __restrict__ enhb, const unsigned short* __restrict__ geo,
    const short* __restrict__ wqT, const short* __restrict__ wkT, const short* __restrict__ wvT,
    const float* __restrict__ bq, const float* __restrict__ bk, const float* __restrict__ bv,
    unsigned short* __restrict__ qo, unsigned short* __restrict__ ko, unsigned short* __restrict__ vo)
{
  const int tid = threadIdx.x, blk = blockIdx.x;
  const int m = blk / 72, rem = blk % 72;
  const int rt = rem / 3, ct = rem % 3;
  const int wave = tid >> 6, lane = tid & 63, quad = lane >> 4, l16 = lane & 15;
  const short* WT = (m==0)?wqT:(m==1)?wkT:wvT;
  const float* Bv = (m==0)?bq:(m==1)?bk:bv;
  unsigned short* Y = (m==0)?qo:(m==1)?ko:vo;
  const short* X = (const short*)((m==0)? enhb : geo);
  const float oscale = (m==0)? 0.10206207261596577f : 1.0f;
  const int row0 = rt*32;
  const int col0 = ct*256 + wave*64;

  f32x4 acc[2][4];
  #pragma unroll
  for (int rb=0;rb<2;++rb)
    #pragma unroll
    for (int cb=0;cb<4;++cb) acc[rb][cb] = (f32x4){0.f,0.f,0.f,0.f};

  for (int ks = 0; ks < 24; ++ks){
    bf16x8 af[2];
    #pragma unroll
    for (int rb=0;rb<2;++rb)
      af[rb] = *(const bf16x8*)&X[(size_t)(row0 + rb*16 + l16)*DD + ks*32 + quad*8];
    #pragma unroll
    for (int cb=0;cb<4;++cb){
      bf16x8 bw = *(const bf16x8*)&WT[(size_t)(col0 + cb*16 + l16)*DD + ks*32 + quad*8];
      #pragma unroll
      for (int rb=0;rb<2;++rb)
        acc[rb][cb] = __builtin_amdgcn_mfma_f32_16x16x32_bf16(af[rb], bw, acc[rb][cb], 0,0,0);
    }
  }
  #pragma unroll
  for (int cb=0;cb<4;++cb){
    int col = col0 + cb*16 + l16;
    float bb = Bv[col];
    #pragma unroll
    for (int rb=0;rb<2;++rb){
      #pragma unroll
      for (int r=0;r<4;++r){
        int row = row0 + rb*16 + quad*4 + r;
        Y[(size_t)row*DD + col] = f_bits((acc[rb][cb][r] + bb)*oscale);
      }
    }
  }
}

// ================= attention =================
__global__ __launch_bounds__(256) void k_attn(
    const unsigned short* __restrict__ qws, const unsigned short* __restrict__ kws,
    const unsigned short* __restrict__ vws, unsigned short* __restrict__ ows)
{
  __shared__ short kt[64*104];
  __shared__ short vt[64*104];
  __shared__ float st[32*66];
  __shared__ float lsum[32];
  const int tid = threadIdx.x;
  const int blk = blockIdx.x;
  const int b = blk / (NHH*12); int rem = blk % (NHH*12);
  const int h = rem / 12; const int qt = rem % 12; const int q0 = qt*32;
  const int sq = tid >> 3, jp = tid & 7;
  const int qp = tid >> 4, dp = tid & 15;
  unsigned qreg[48];
  {
    const unsigned* qr = (const unsigned*)(qws + (size_t)(b*NN + q0 + sq)*DD + h*DHH);
    #pragma unroll
    for (int d2 = 0; d2 < 48; ++d2) qreg[d2] = qr[d2];
  }
  if (tid < 32) lsum[tid] = 0.f;
  float Oacc[2][6];
  #pragma unroll
  for (int a = 0; a < 2; ++a)
    #pragma unroll
    for (int m = 0; m < 6; ++m) Oacc[a][m] = 0.f;

  for (int jt = 0; jt < 6; ++jt){
    const int j0 = jt * 64;
    __syncthreads();
    for (int x = tid; x < 64*48; x += 256){
      int jl = x / 48, du = x % 48;
      size_t rowoff = (size_t)(b*NN + j0 + jl)*DD + h*DHH;
      ((unsigned*)&kt[jl*104])[du] = ((const unsigned*)(kws + rowoff))[du];
      ((unsigned*)&vt[jl*104])[du] = ((const unsigned*)(vws + rowoff))[du];
    }
    __syncthreads();
    float lpart = 0.f;
    #pragma unroll
    for (int jj = 0; jj < 8; ++jj){
      int j = jp*8 + jj;
      const uint4* kr4 = (const uint4*)&kt[j*104];
      float s = 0.f;
      #pragma unroll
      for (int d4 = 0; d4 < 12; ++d4){
        uint4 kk = kr4[d4];
        unsigned q0r = qreg[4*d4], q1r = qreg[4*d4+1], q2r = qreg[4*d4+2], q3r = qreg[4*d4+3];
        s += lo_f(kk.x)*lo_f(q0r) + hi_f(kk.x)*hi_f(q0r);
        s += lo_f(kk.y)*lo_f(q1r) + hi_f(kk.y)*hi_f(q1r);
        s += lo_f(kk.z)*lo_f(q2r) + hi_f(kk.z)*hi_f(q2r);
        s += lo_f(kk.w)*lo_f(q3r) + hi_f(kk.w)*hi_f(q3r);
      }
      float p = __expf(s);
      st[sq*66 + j] = p;
      lpart += p;
    }
    lpart += __shfl_xor(lpart,1);
    lpart += __shfl_xor(lpart,2);
    lpart += __shfl_xor(lpart,4);
    if (jp == 0) lsum[sq] += lpart;
    __syncthreads();
    #pragma unroll 4
    for (int j = 0; j < 64; ++j){
      float p0 = st[(2*qp)*66 + j];
      float p1 = st[(2*qp+1)*66 + j];
      const unsigned* vr = (const unsigned*)&vt[j*104 + dp*6];
      #pragma unroll
      for (int m = 0; m < 3; ++m){
        unsigned vv = vr[m];
        float v0 = lo_f(vv), v1 = hi_f(vv);
        Oacc[0][2*m]   += p0*v0; Oacc[0][2*m+1] += p0*v1;
        Oacc[1][2*m]   += p1*v0; Oacc[1][2*m+1] += p1*v1;
      }
    }
  }
  __syncthreads();
  float l0 = 1.f / lsum[2*qp], l1 = 1.f / lsum[2*qp+1];
  size_t ob = (size_t)(b*NN + q0)*DD + h*DHH + dp*6;
  #pragma unroll
  for (int m = 0; m < 6; ++m){
    ows[ob + (size_t)(2*qp)*DD + m]   = f_bits(Oacc[0][m]*l0);
    ows[ob + (size_t)(2*qp+1)*DD + m] = f_bits(Oacc[1][m]*l1);
  }
}

// ================= output projection via MFMA + residual =================
__global__ __launch_bounds__(256, 4) void k_out(
    const unsigned short* __restrict__ ows, const float* __restrict__ enh,
    const short* __restrict__ woT, const float* __restrict__ bo, float* __restrict__ out)
{
  const int tid = threadIdx.x, blk = blockIdx.x;
  const int rt = blk / 3, ct = blk % 3;
  const int wave = tid >> 6, lane = tid & 63, quad = lane >> 4, l16 = lane & 15;
  const int row0 = rt*32;
  const int col0 = ct*256 + wave*64;
  f32x4 acc[2][4];
  #pragma unroll
  for (int rb=0;rb<2;++rb)
    #pragma unroll
    for (int cb=0;cb<4;++cb) acc[rb][cb] = (f32x4){0.f,0.f,0.f,0.f};
  for (int ks = 0; ks < 24; ++ks){
    bf16x8 af[2];
    #pragma unroll
    for (int rb=0;rb<2;++rb)
      af[rb] = *(const bf16x8*)&((const short*)ows)[(size_t)(row0 + rb*16 + l16)*DD + ks*32 + quad*8];
    #pragma unroll
    for (int cb=0;cb<4;++cb){
      bf16x8 bw = *(const bf16x8*)&woT[(size_t)(col0 + cb*16 + l16)*DD + ks*32 + quad*8];
      #pragma unroll
      for (int rb=0;rb<2;++rb)
        acc[rb][cb] = __builtin_amdgcn_mfma_f32_16x16x32_bf16(af[rb], bw, acc[rb][cb], 0,0,0);
    }
  }
  #pragma unroll
  for (int cb=0;cb<4;++cb){
    int col = col0 + cb*16 + l16;
    float bb = bo[col];
    #pragma unroll
    for (int rb=0;rb<2;++rb){
      #pragma unroll
      for (int r=0;r<4;++r){
        size_t idx = (size_t)(row0 + rb*16 + quad*4 + r)*DD + col;
        out[idx] = enh[idx] + 0.5f*(acc[rb][cb][r] + bb);
      }
    }
  }
}

extern "C" void kernel_launch(void* const* d_in, const int* in_sizes, int n_in,
                              void* d_out, int out_size, void* d_ws, size_t ws_size,
                              hipStream_t stream) {
  const float* coord = (const float*)d_in[0];
  const float* feat  = (const float*)d_in[1];
  const int*   lab   = (const int*)d_in[2];
  const float* ge_w1 = (const float*)d_in[3];
  const float* ge_b1 = (const float*)d_in[4];
  const float* ge_g1 = (const float*)d_in[5];
  const float* ge_be1= (const float*)d_in[6];
  const float* ge_w2 = (const float*)d_in[7];
  const float* ge_b2 = (const float*)d_in[8];
  const float* ge_g2 = (const float*)d_in[9];
  const float* ge_be2= (const float*)d_in[10];
  const float* ag_w1 = (const float*)d_in[11];
  const float* ag_b1 = (const float*)d_in[12];
  const float* ag_g1 = (const float*)d_in[13];
  const float* ag_be1= (const float*)d_in[14];
  const float* ag_w2 = (const float*)d_in[15];
  const float* ag_b2 = (const float*)d_in[16];
  const float* ag_g2 = (const float*)d_in[17];
  const float* ag_be2= (const float*)d_in[18];
  const float* wq = (const float*)d_in[19];
  const float* bq = (const float*)d_in[20];
  const float* wk = (const float*)d_in[21];
  const float* bk = (const float*)d_in[22];
  const float* wv = (const float*)d_in[23];
  const float* bv = (const float*)d_in[24];
  const float* wo = (const float*)d_in[25];
  const float* bo = (const float*)d_in[26];

  // Workspace 15,906,048 B. gv|mf|mg|cntw are contiguous -> single zero range.
  char* w = (char*)d_ws;
  unsigned short* geo_bf = (unsigned short*)(w);              // 1,179,648  [ow overlay]
  float*          enh_f  = (float*)(w + 1179648);             // 2,359,296
  unsigned short* enh_bf = (unsigned short*)(w + 3538944);    // 1,179,648
  unsigned short* qw_bf  = (unsigned short*)(w + 4718592);    // 1,179,648
  unsigned short* kw_bf  = (unsigned short*)(w + 5898240);    // 1,179,648
  unsigned short* vw_bf  = (unsigned short*)(w + 7077888);    // 1,179,648
  float*          gv     = (float*)(w + 8257536);             //   798,720
  float*          mf     = (float*)(w + 9056256);             //   393,216
  float*          mg     = (float*)(w + 9449472);             //   393,216
  float*          cntw   = (float*)(w + 9842688);             //       512
  float*          comb   = (float*)(w + 9843200);             //   393,216
  short*          w2T    = (short*)(w + 10236416);            //   393,216
  short*          w2r    = (short*)(w + 10629632);            //   393,216
  short*          w1t    = (short*)(w + 11022848);            //    16,384
  short*          Gm     = (short*)(w + 11039232);            //   147,456
  float*          g1s    = (float*)(w + 11186688);            //       512
  float*          gscal  = (float*)(w + 11187200);            //       256
  short*          wqT    = (short*)(w + 11187456);            // 1,179,648
  short*          wkT    = (short*)(w + 12367104);            // 1,179,648
  short*          wvT    = (short*)(w + 13546752);            // 1,179,648
  short*          woT    = (short*)(w + 14726400);            // 1,179,648
  unsigned short* ow_bf  = geo_bf;

  hipLaunchKernelGGL(k_prep,    dim3(2973),  dim3(256), 0, stream,
                     ge_w2, ge_w1, wq, wk, wv, wo,
                     gv, w2T, w2r, wqT, wkT, wvT, woT, w1t);
  hipLaunchKernelGGL(k_gprep,   dim3(258),   dim3(256), 0, stream,
                     w2T, ge_b2, w1t, ge_b1, Gm, gscal, g1s);
  hipLaunchKernelGGL(k_geo,     dim3(4608),  dim3(256), 0, stream,
                     coord, w1t, ge_b1, ge_g1, ge_be1, Gm, gscal, g1s, gv);
  hipLaunchKernelGGL(k_geofin,  dim3(768),   dim3(256), 0, stream,
                     gv, w2r, ge_b2, ge_g2, ge_be2, geo_bf);
  hipLaunchKernelGGL(k_scat,    dim3(768),   dim3(256), 0, stream,
                     lab, feat, geo_bf, mf, mg, cntw);
  hipLaunchKernelGGL(k_agg,     dim3(128),   dim3(256), 0, stream,
                     mf, mg, cntw, ag_w1, ag_b1, ag_g1, ag_be1, ag_w2, ag_b2, ag_g2, ag_be2, comb);
  hipLaunchKernelGGL(k_enhance, dim3(2304),  dim3(256), 0, stream,
                     feat, lab, cntw, comb, enh_f, enh_bf);
  hipLaunchKernelGGL(k_qkv,     dim3(216),   dim3(256), 0, stream,
                     enh_bf, geo_bf, wqT, wkT, wvT, bq, bk, bv, qw_bf, kw_bf, vw_bf);
  hipLaunchKernelGGL(k_attn,    dim3(192),   dim3(256), 0, stream,
                     qw_bf, kw_bf, vw_bf, ow_bf);
  hipLaunchKernelGGL(k_out,     dim3(72),    dim3(256), 0, stream,
                     ow_bf, enh_f, woT, bo, (float*)d_out);
}

// Round 10
// 550.455 us; speedup vs baseline: 1.5489x; 1.5489x over previous
//
#include <hip/hip_runtime.h>
#include <hip/hip_bf16.h>
#include <stdint.h>
#include <stddef.h>

#define BB 2
#define NN 384
#define DD 768
#define HH 256
#define SS 64
#define NHH 8
#define DHH 96

typedef __attribute__((ext_vector_type(8))) short bf16x8;
typedef __attribute__((ext_vector_type(4))) float f32x4;

__device__ __forceinline__ float bits_f(unsigned short u){
  unsigned x = ((unsigned)u) << 16; float f; __builtin_memcpy(&f, &x, 4); return f;
}
__device__ __forceinline__ unsigned short f_bits(float a){
  unsigned x; __builtin_memcpy(&x, &a, 4);
  unsigned r = x + 0x7fffu + ((x >> 16) & 1u);
  return (unsigned short)(r >> 16);
}
__device__ __forceinline__ float lo_f(unsigned u){ unsigned x = u << 16; float f; __builtin_memcpy(&f,&x,4); return f; }
__device__ __forceinline__ float hi_f(unsigned u){ unsigned x = u & 0xffff0000u; float f; __builtin_memcpy(&f,&x,4); return f; }

// ================= prep: zeroing + all transposes (LDS-tiled, coalesced) =================
__global__ __launch_bounds__(256) void k_prep(
    const float* __restrict__ w2, const float* __restrict__ w1g,
    const float* __restrict__ wq, const float* __restrict__ wk,
    const float* __restrict__ wv, const float* __restrict__ wo,
    float* __restrict__ zf, short* __restrict__ w2T, short* __restrict__ w2r,
    short* __restrict__ wqT, short* __restrict__ wkT, short* __restrict__ wvT,
    short* __restrict__ woT, short* __restrict__ w1t)
{
  __shared__ short tile[64*66];
  const int tid = threadIdx.x, blk = blockIdx.x;
  if (blk < 1549){
    int idx = blk*256 + tid;
    if (idx < 396416) zf[idx] = 0.f;
    return;
  }
  if (blk < 1597){            // w2 [256,768] -> w2T [768,256]
    int t = blk - 1549;
    int r0 = (t/12)*64, c0 = (t%12)*64;
    int g = tid >> 6, c = tid & 63;
    #pragma unroll
    for (int i=0;i<16;++i){
      int r = i*4 + g;
      tile[r*66 + c] = (short)f_bits(w2[(size_t)(r0+r)*768 + c0 + c]);
    }
    __syncthreads();
    #pragma unroll
    for (int i=0;i<16;++i){
      int cc = i*4 + g, rr = c;
      w2T[(size_t)(c0+cc)*256 + r0 + rr] = tile[rr*66 + cc];
    }
    return;
  }
  if (blk < 2365){            // w2r: row-major bf16 copy
    int idx = (blk-1597)*256 + tid;
    w2r[idx] = (short)f_bits(w2[idx]);
    return;
  }
  if (blk < 2941){            // attn weights [768,768] -> T[n][k]
    int t = blk - 2365;
    int mat = t / 144, tt = t % 144;
    const float* W = (mat==0)?wq:(mat==1)?wk:(mat==2)?wv:wo;
    short* T = (mat==0)?wqT:(mat==1)?wkT:(mat==2)?wvT:woT;
    int r0 = (tt/12)*64, c0 = (tt%12)*64;
    int g = tid >> 6, c = tid & 63;
    #pragma unroll
    for (int i=0;i<16;++i){
      int r = i*4 + g;
      tile[r*66 + c] = (short)f_bits(W[(size_t)(r0+r)*768 + c0 + c]);
    }
    __syncthreads();
    #pragma unroll
    for (int i=0;i<16;++i){
      int cc = i*4 + g, rr = c;
      T[(size_t)(c0+cc)*768 + r0 + rr] = tile[rr*66 + cc];
    }
    return;
  }
  {                           // w1t [256c][32k], K padded
    int idx = (blk-2941)*256 + tid;
    int c = idx >> 5, kk = idx & 31;
    w1t[idx] = (kk < 9) ? (short)f_bits(w1g[kk*256 + c]) : (short)0;
  }
}

// ================= Gram prep: Gm[288][256] (rows 256=s1,257=wb,258+=0), gscal, w1 stats =================
__global__ __launch_bounds__(256) void k_gprep(const short* __restrict__ w2T,
                                               const float* __restrict__ b2,
                                               const short* __restrict__ w1t,
                                               const float* __restrict__ b1,
                                               short* __restrict__ Gm, float* __restrict__ gscal,
                                               float* __restrict__ g1s){
  __shared__ float red[8];
  const int tid = threadIdx.x, blk = blockIdx.x;
  const unsigned short* wt = (const unsigned short*)w2T;
  if (blk < 256){
    float acc = 0.f;
    for (int c = 0; c < 768; ++c){
      float a = bits_f(wt[c*256 + blk]);
      float x = bits_f(wt[c*256 + tid]);
      acc += a * x;
    }
    Gm[blk*256 + tid] = (short)f_bits(acc);
  } else if (blk == 256){
    float sa = 0.f, wa = 0.f;
    for (int c = 0; c < 768; ++c){
      float x = bits_f(wt[c*256 + tid]);
      float bb = b2[c];
      sa += x; wa += x * bb;
    }
    Gm[256*256 + tid] = (short)f_bits(sa);
    Gm[257*256 + tid] = (short)f_bits(wa);
    #pragma unroll
    for (int rr = 258; rr < 288; ++rr) Gm[rr*256 + tid] = 0;
    float pb = 0.f, pbb = 0.f;
    for (int c = tid; c < 768; c += 256){ float bb = b2[c]; pb += bb; pbb += bb*bb; }
    for (int m = 32; m >= 1; m >>= 1){ pb += __shfl_xor(pb,m); pbb += __shfl_xor(pbb,m); }
    if ((tid & 63) == 0){ red[tid>>6] = pb; red[4+(tid>>6)] = pbb; }
    __syncthreads();
    if (tid == 0){ gscal[0] = red[0]+red[1]+red[2]+red[3]; gscal[1] = red[4]+red[5]+red[6]+red[7]; }
  } else {
    // g1s[0..8]=s1a, [9..17]=w1b1, [18..98]=G1(9x9), [99]=Sb1, [100]=Sb1b
    const unsigned short* w1u = (const unsigned short*)w1t;
    if (tid < 81){
      int i = tid / 9, j = tid % 9;
      float acc = 0.f;
      for (int c = 0; c < 256; ++c)
        acc += bits_f(w1u[c*32 + i]) * bits_f(w1u[c*32 + j]);
      g1s[18 + tid] = acc;
    } else if (tid < 90){
      int i = tid - 81;
      float sa = 0.f, sb = 0.f;
      for (int c = 0; c < 256; ++c){
        float x = bits_f(w1u[c*32 + i]);
        sa += x; sb += x * b1[c];
      }
      g1s[i] = sa; g1s[9 + i] = sb;
    } else if (tid == 90){
      float pb = 0.f, pbb = 0.f;
      for (int c = 0; c < 256; ++c){ float bb = b1[c]; pb += bb; pbb += bb*bb; }
      g1s[99] = pb; g1s[100] = pbb;
    }
  }
}

// ================= geometric encoder; WG=(pair,jt), 256 thr, 4 waves, 3 WG/CU =================
// launch_bounds(256,3) -> 170-reg cap: acc[4][4]+eacc (80 acc) + ~80 arch fits, no scratch spill.
__global__ __launch_bounds__(256, 3) void k_geo(
    const float* __restrict__ coord, const short* __restrict__ w1t,
    const float* __restrict__ b1g, const float* __restrict__ g1g, const float* __restrict__ be1g,
    const short* __restrict__ Gm, const float* __restrict__ gscal,
    const float* __restrict__ g1s, float* __restrict__ gv)
{
  __shared__ short relbf[64*36];
  __shared__ short h_bf[64*256];   // chunk-swizzled: phys_chunk=((col>>3)+row)&31
  __shared__ float rmean[64], rrstd[64];
  __shared__ float msum[64], wbsum[64], qsum[64];

  const int tid = threadIdx.x;
  const int pair = blockIdx.x % 768;
  const int jt   = blockIdx.x / 768;
  const int j0 = jt * 64;
  const int b = pair / NN;

  // ---- phase 1: rel rows + exact LN1 stats via 9x9 Gram
  if (tid < 64){
    int j = j0 + tid;
    float cix = coord[pair*3+0], ciy = coord[pair*3+1], ciz = coord[pair*3+2];
    float dx = cix - coord[(b*NN+j)*3+0];
    float dy = ciy - coord[(b*NN+j)*3+1];
    float dz = ciz - coord[(b*NN+j)*3+2];
    float dist = sqrtf(dx*dx + dy*dy + dz*dz);
    float inv = 1.f / fmaxf(dist, 1e-12f);
    float x = dx*inv, y = dy*inv, z = dz*inv;
    float rv[9];
    rv[0]=dist; rv[1]=x; rv[2]=y; rv[3]=z; rv[4]=0.f; rv[5]=0.f;
    rv[6]=y*z; rv[7]=x*y; rv[8]=x*z;
    short* rr = &relbf[tid*36];
    float rbf[9];
    #pragma unroll
    for (int k=0;k<9;++k){
      unsigned short hb = f_bits(rv[k]);
      rr[k] = (short)hb; rbf[k] = bits_f(hb);
    }
    #pragma unroll
    for (int k=9;k<32;++k) rr[k]=0;
    float s = g1s[99], ssq = g1s[100];
    #pragma unroll
    for (int i=0;i<9;++i){
      s += rbf[i]*g1s[i];
      ssq += 2.f*rbf[i]*g1s[9+i];
      #pragma unroll
      for (int jj=0;jj<9;++jj) ssq += rbf[i]*rbf[jj]*g1s[18+i*9+jj];
    }
    float mean = s*(1.f/256.f);
    float var  = ssq*(1.f/256.f) - mean*mean;
    rmean[tid] = mean; rrstd[tid] = rsqrtf(var + 1e-5f);
  } else if (tid < 128){
    qsum[tid-64] = 0.f;
  }
  __syncthreads();

  const int wave = tid >> 6, lane = tid & 63, quad = lane >> 4, l16 = lane & 15;

  // ---- phase 2: MFMA mm1 + in-register LN1/ReLU -> h_bf (no shuffles/atomics)
  {
    bf16x8 af[4];
    #pragma unroll
    for (int rb=0;rb<4;++rb)
      af[rb] = *(const bf16x8*)&relbf[(rb*16 + l16)*36 + quad*8];
    f32x4 hacc[4][4];
    #pragma unroll
    for (int ci=0;ci<4;++ci){
      int cb = wave*4 + ci;
      bf16x8 bfw = *(const bf16x8*)&w1t[(cb*16 + l16)*32 + quad*8];
      #pragma unroll
      for (int rb=0;rb<4;++rb)
        hacc[ci][rb] = __builtin_amdgcn_mfma_f32_16x16x32_bf16(af[rb], bfw, (f32x4){0.f,0.f,0.f,0.f}, 0,0,0);
    }
    f32x4 rmv[4], rsv[4];
    #pragma unroll
    for (int rb=0;rb<4;++rb){
      rmv[rb] = *(const f32x4*)&rmean[rb*16 + quad*4];
      rsv[rb] = *(const f32x4*)&rrstd[rb*16 + quad*4];
    }
    #pragma unroll
    for (int ci=0;ci<4;++ci){
      int col = (wave*4+ci)*16 + l16;
      float b1c = b1g[col], g1c = g1g[col], be1c = be1g[col];
      int chb = col >> 3, lo = col & 7;
      #pragma unroll
      for (int rb=0;rb<4;++rb){
        #pragma unroll
        for (int r=0;r<4;++r){
          int row = rb*16 + quad*4 + r;
          float hn = (hacc[ci][rb][r] + b1c - rmv[rb][r]) * rsv[rb][r] * g1c + be1c;
          h_bf[row*256 + ((chb + row)&31)*8 + lo] = (short)f_bits(fmaxf(hn, 0.f));
        }
      }
    }
  }
  __syncthreads();

  // ---- phase 3: U = H@Gm_ext; wave0 ext tile -> msum/wbsum; Q_j = sum U.h
  {
    f32x4 acc[4][4];
    #pragma unroll
    for (int ci=0;ci<4;++ci)
      #pragma unroll
      for (int rb=0;rb<4;++rb) acc[ci][rb] = (f32x4){0.f,0.f,0.f,0.f};
    f32x4 eacc[4];
    #pragma unroll
    for (int rb=0;rb<4;++rb) eacc[rb] = (f32x4){0.f,0.f,0.f,0.f};
    for (int ks=0;ks<8;++ks){
      bf16x8 a4[4];
      #pragma unroll
      for (int rb=0;rb<4;++rb){
        int row = rb*16 + l16;
        a4[rb] = *(const bf16x8*)&h_bf[row*256 + (((ks*4 + quad) + row)&31)*8];
      }
      #pragma unroll
      for (int ci=0;ci<4;++ci){
        int n = (wave*4+ci)*16 + l16;
        bf16x8 bg = *(const bf16x8*)&Gm[n*256 + ks*32 + quad*8];
        #pragma unroll
        for (int rb=0;rb<4;++rb)
          acc[ci][rb] = __builtin_amdgcn_mfma_f32_16x16x32_bf16(a4[rb], bg, acc[ci][rb], 0,0,0);
      }
      if (wave == 0){
        bf16x8 bge = *(const bf16x8*)&Gm[(256 + l16)*256 + ks*32 + quad*8];
        #pragma unroll
        for (int rb=0;rb<4;++rb)
          eacc[rb] = __builtin_amdgcn_mfma_f32_16x16x32_bf16(a4[rb], bge, eacc[rb], 0,0,0);
      }
    }
    if (wave == 0 && l16 < 2){
      float* dst = (l16 == 0) ? msum : wbsum;
      #pragma unroll
      for (int rb=0;rb<4;++rb)
        #pragma unroll
        for (int r=0;r<4;++r) dst[rb*16 + quad*4 + r] = eacc[rb][r];
    }
    #pragma unroll
    for (int rb=0;rb<4;++rb){
      #pragma unroll
      for (int r=0;r<4;++r){
        int row = rb*16 + quad*4 + r;
        float qp = 0.f;
        #pragma unroll
        for (int ci=0;ci<4;++ci){
          int col = (wave*4+ci)*16 + l16;
          float hv = bits_f((unsigned short)h_bf[row*256 + (((col>>3)+row)&31)*8 + (col&7)]);
          qp += acc[ci][rb][r] * hv;
        }
        qp += __shfl_xor(qp,1);
        qp += __shfl_xor(qp,2);
        qp += __shfl_xor(qp,4);
        qp += __shfl_xor(qp,8);
        if (l16 == 0) atomicAdd(&qsum[row], qp);
      }
    }
  }
  __syncthreads();
  if (tid < 64){
    float Sb = gscal[0], Sbb = gscal[1];
    float m2 = (msum[tid] + Sb)*(1.f/768.f);
    float ssq = qsum[tid] + 2.f*wbsum[tid] + Sbb;
    float var = ssq*(1.f/768.f) - m2*m2;
    rmean[tid] = m2; rrstd[tid] = rsqrtf(var + 1e-5f);
  }
  __syncthreads();
  if (tid < 64){
    float rr = rrstd[tid], tt = rmean[tid]*rrstd[tid];
    for (int m = 32; m >= 1; m >>= 1){ rr += __shfl_xor(rr,m); tt += __shfl_xor(tt,m); }
    if (tid == 0){
      atomicAdd(&gv[pair*260 + 256], rr);
      atomicAdd(&gv[pair*260 + 257], tt);
    }
  }
  {
    int col = tid, chb = col >> 3, lo = col & 7;
    float v = 0.f;
    #pragma unroll 8
    for (int j = 0; j < 64; ++j)
      v += rrstd[j] * bits_f((unsigned short)h_bf[j*256 + ((chb + j)&31)*8 + lo]);
    atomicAdd(&gv[pair*260 + col], v);
  }
}

// ================= finalize geo (coalesced w2r reads) =================
__global__ __launch_bounds__(256) void k_geofin(
    const float* __restrict__ gv, const short* __restrict__ w2r,
    const float* __restrict__ b2g, const float* __restrict__ g2g,
    const float* __restrict__ be2g, unsigned short* __restrict__ geo){
  __shared__ float V[256];
  __shared__ float RT[2];
  const int tid = threadIdx.x, pair = blockIdx.x;
  V[tid] = gv[pair*260 + tid];
  if (tid < 2) RT[tid] = gv[pair*260 + 256 + tid];
  __syncthreads();
  float R = RT[0], T = RT[1];
  const unsigned short* wr = (const unsigned short*)w2r;
  float a0 = 0.f, a1 = 0.f, a2 = 0.f;
  #pragma unroll 4
  for (int k = 0; k < 256; ++k){
    float vk = V[k];
    const unsigned short* row = wr + (size_t)k*768;
    a0 += vk * bits_f(row[tid]);
    a1 += vk * bits_f(row[tid+256]);
    a2 += vk * bits_f(row[tid+512]);
  }
  size_t base = (size_t)pair*DD;
  geo[base + tid]       = f_bits(g2g[tid]    *(a0 + b2g[tid]    *R - T)*(1.f/384.f) + be2g[tid]);
  geo[base + tid + 256] = f_bits(g2g[tid+256]*(a1 + b2g[tid+256]*R - T)*(1.f/384.f) + be2g[tid+256]);
  geo[base + tid + 512] = f_bits(g2g[tid+512]*(a2 + b2g[tid+512]*R - T)*(1.f/384.f) + be2g[tid+512]);
}

// ================= per-point scatter (atomics) =================
__global__ __launch_bounds__(256) void k_scat(
    const int* __restrict__ lab, const float* __restrict__ feat,
    const unsigned short* __restrict__ geo,
    float* __restrict__ mf, float* __restrict__ mg, float* __restrict__ cntw)
{
  const int tid = threadIdx.x, bn = blockIdx.x;
  const int b = bn / NN;
  const int s = lab[bn];
  const size_t base = (size_t)(b*SS + s)*DD;
  if (tid == 0) atomicAdd(&cntw[b*SS + s], 1.0f);
  #pragma unroll
  for (int u = 0; u < 3; ++u){
    int c = tid + 256*u;
    atomicAdd(&mf[base + c], feat[(size_t)bn*DD + c]);
    atomicAdd(&mg[base + c], bits_f(geo[(size_t)bn*DD + c]));
  }
}

// ================= aggregator MLP + combine =================
__global__ __launch_bounds__(256) void k_agg(
    const float* __restrict__ mf, const float* __restrict__ mg,
    const float* __restrict__ cntw,
    const float* __restrict__ w1g, const float* __restrict__ b1g,
    const float* __restrict__ g1g, const float* __restrict__ be1g,
    const float* __restrict__ w2g, const float* __restrict__ b2g,
    const float* __restrict__ g2g, const float* __restrict__ be2g,
    float* __restrict__ comb)
{
  __shared__ float xr[DD];
  __shared__ float hr[HH];
  __shared__ float red[8];
  const int tid = threadIdx.x;
  const size_t base = (size_t)blockIdx.x * DD;
  const float inv = 1.f / fmaxf(cntw[blockIdx.x], 1.f);
  for (int c = tid; c < DD; c += 256) xr[c] = mf[base + c]*inv;
  __syncthreads();
  float a = b1g[tid];
  #pragma unroll 4
  for (int k = 0; k < DD; ++k) a += xr[k]*w1g[k*HH + tid];
  float s = a, q = a*a;
  for (int m = 32; m >= 1; m >>= 1){ s += __shfl_xor(s,m); q += __shfl_xor(q,m); }
  if ((tid & 63) == 0){ red[tid>>6] = s; red[4+(tid>>6)] = q; }
  __syncthreads();
  s = red[0]+red[1]+red[2]+red[3]; q = red[4]+red[5]+red[6]+red[7];
  float mean = s*(1.f/HH), var = q*(1.f/HH) - mean*mean, rstd = rsqrtf(var + 1e-5f);
  float h = fmaxf((a-mean)*rstd*g1g[tid] + be1g[tid], 0.f);
  hr[tid] = h;
  __syncthreads();
  float a2[3];
  #pragma unroll
  for (int u = 0; u < 3; ++u){
    int c = tid + 256*u;
    float t = b2g[c];
    #pragma unroll 4
    for (int k = 0; k < HH; ++k) t += hr[k]*w2g[k*DD + c];
    a2[u] = t;
  }
  float s2 = a2[0]+a2[1]+a2[2], q2 = a2[0]*a2[0]+a2[1]*a2[1]+a2[2]*a2[2];
  for (int m = 32; m >= 1; m >>= 1){ s2 += __shfl_xor(s2,m); q2 += __shfl_xor(q2,m); }
  __syncthreads();
  if ((tid & 63) == 0){ red[tid>>6] = s2; red[4+(tid>>6)] = q2; }
  __syncthreads();
  s2 = red[0]+red[1]+red[2]+red[3]; q2 = red[4]+red[5]+red[6]+red[7];
  float mean2 = s2*(1.f/DD), rstd2 = rsqrtf(q2*(1.f/DD) - mean2*mean2 + 1e-5f);
  #pragma unroll
  for (int u = 0; u < 3; ++u){
    int c = tid + 256*u;
    comb[base + c] = (a2[u]-mean2)*rstd2*g2g[c] + be2g[c] + mg[base + c]*inv;
  }
}

// ================= gather + enhanced (fp32 + bf16 out) =================
__global__ void k_enhance(const float* __restrict__ feat, const int* __restrict__ lab,
                          const float* __restrict__ cntw, const float* __restrict__ comb,
                          float* __restrict__ enh, unsigned short* __restrict__ enhb)
{
  int idx = blockIdx.x * 256 + threadIdx.x;
  int c = idx % DD; int bn = idx / DD; int b = bn / NN;
  int l = lab[bn];
  float f = feat[idx];
  float cg = comb[(size_t)(b*SS + l)*DD + c];
  float cnt = cntw[b*SS + l];
  float e = (cnt >= 2.0f) ? (0.7f*f + 0.3f*cg) : f;
  enh[idx] = e;
  enhb[idx] = f_bits(e);
}

// ================= q/k/v projections via MFMA =================
__global__ __launch_bounds__(256, 4) void k_qkv(
    const unsigned short* __restrict__ enhb, const unsigned short* __restrict__ geo,
    const short* __restrict__ wqT, const short* __restrict__ wkT, const short* __restrict__ wvT,
    const float* __restrict__ bq, const float* __restrict__ bk, const float* __restrict__ bv,
    unsigned short* __restrict__ qo, unsigned short* __restrict__ ko, unsigned short* __restrict__ vo)
{
  const int tid = threadIdx.x, blk = blockIdx.x;
  const int m = blk / 72, rem = blk % 72;
  const int rt = rem / 3, ct = rem % 3;
  const int wave = tid >> 6, lane = tid & 63, quad = lane >> 4, l16 = lane & 15;
  const short* WT = (m==0)?wqT:(m==1)?wkT:wvT;
  const float* Bv = (m==0)?bq:(m==1)?bk:bv;
  unsigned short* Y = (m==0)?qo:(m==1)?ko:vo;
  const short* X = (const short*)((m==0)? enhb : geo);
  const float oscale = (m==0)? 0.10206207261596577f : 1.0f;
  const int row0 = rt*32;
  const int col0 = ct*256 + wave*64;

  f32x4 acc[2][4];
  #pragma unroll
  for (int rb=0;rb<2;++rb)
    #pragma unroll
    for (int cb=0;cb<4;++cb) acc[rb][cb] = (f32x4){0.f,0.f,0.f,0.f};

  for (int ks = 0; ks < 24; ++ks){
    bf16x8 af[2];
    #pragma unroll
    for (int rb=0;rb<2;++rb)
      af[rb] = *(const bf16x8*)&X[(size_t)(row0 + rb*16 + l16)*DD + ks*32 + quad*8];
    #pragma unroll
    for (int cb=0;cb<4;++cb){
      bf16x8 bw = *(const bf16x8*)&WT[(size_t)(col0 + cb*16 + l16)*DD + ks*32 + quad*8];
      #pragma unroll
      for (int rb=0;rb<2;++rb)
        acc[rb][cb] = __builtin_amdgcn_mfma_f32_16x16x32_bf16(af[rb], bw, acc[rb][cb], 0,0,0);
    }
  }
  #pragma unroll
  for (int cb=0;cb<4;++cb){
    int col = col0 + cb*16 + l16;
    float bb = Bv[col];
    #pragma unroll
    for (int rb=0;rb<2;++rb){
      #pragma unroll
      for (int r=0;r<4;++r){
        int row = row0 + rb*16 + quad*4 + r;
        Y[(size_t)row*DD + col] = f_bits((acc[rb][cb][r] + bb)*oscale);
      }
    }
  }
}

// ================= attention =================
__global__ __launch_bounds__(256) void k_attn(
    const unsigned short* __restrict__ qws, const unsigned short* __restrict__ kws,
    const unsigned short* __restrict__ vws, unsigned short* __restrict__ ows)
{
  __shared__ short kt[64*104];
  __shared__ short vt[64*104];
  __shared__ float st[32*66];
  __shared__ float lsum[32];
  const int tid = threadIdx.x;
  const int blk = blockIdx.x;
  const int b = blk / (NHH*12); int rem = blk % (NHH*12);
  const int h = rem / 12; const int qt = rem % 12; const int q0 = qt*32;
  const int sq = tid >> 3, jp = tid & 7;
  const int qp = tid >> 4, dp = tid & 15;
  unsigned qreg[48];
  {
    const unsigned* qr = (const unsigned*)(qws + (size_t)(b*NN + q0 + sq)*DD + h*DHH);
    #pragma unroll
    for (int d2 = 0; d2 < 48; ++d2) qreg[d2] = qr[d2];
  }
  if (tid < 32) lsum[tid] = 0.f;
  float Oacc[2][6];
  #pragma unroll
  for (int a = 0; a < 2; ++a)
    #pragma unroll
    for (int m = 0; m < 6; ++m) Oacc[a][m] = 0.f;

  for (int jt = 0; jt < 6; ++jt){
    const int j0 = jt * 64;
    __syncthreads();
    for (int x = tid; x < 64*48; x += 256){
      int jl = x / 48, du = x % 48;
      size_t rowoff = (size_t)(b*NN + j0 + jl)*DD + h*DHH;
      ((unsigned*)&kt[jl*104])[du] = ((const unsigned*)(kws + rowoff))[du];
      ((unsigned*)&vt[jl*104])[du] = ((const unsigned*)(vws + rowoff))[du];
    }
    __syncthreads();
    float lpart = 0.f;
    #pragma unroll
    for (int jj = 0; jj < 8; ++jj){
      int j = jp*8 + jj;
      const uint4* kr4 = (const uint4*)&kt[j*104];
      float s = 0.f;
      #pragma unroll
      for (int d4 = 0; d4 < 12; ++d4){
        uint4 kk = kr4[d4];
        unsigned q0r = qreg[4*d4], q1r = qreg[4*d4+1], q2r = qreg[4*d4+2], q3r = qreg[4*d4+3];
        s += lo_f(kk.x)*lo_f(q0r) + hi_f(kk.x)*hi_f(q0r);
        s += lo_f(kk.y)*lo_f(q1r) + hi_f(kk.y)*hi_f(q1r);
        s += lo_f(kk.z)*lo_f(q2r) + hi_f(kk.z)*hi_f(q2r);
        s += lo_f(kk.w)*lo_f(q3r) + hi_f(kk.w)*hi_f(q3r);
      }
      float p = __expf(s);
      st[sq*66 + j] = p;
      lpart += p;
    }
    lpart += __shfl_xor(lpart,1);
    lpart += __shfl_xor(lpart,2);
    lpart += __shfl_xor(lpart,4);
    if (jp == 0) lsum[sq] += lpart;
    __syncthreads();
    #pragma unroll 4
    for (int j = 0; j < 64; ++j){
      float p0 = st[(2*qp)*66 + j];
      float p1 = st[(2*qp+1)*66 + j];
      const unsigned* vr = (const unsigned*)&vt[j*104 + dp*6];
      #pragma unroll
      for (int m = 0; m < 3; ++m){
        unsigned vv = vr[m];
        float v0 = lo_f(vv), v1 = hi_f(vv);
        Oacc[0][2*m]   += p0*v0; Oacc[0][2*m+1] += p0*v1;
        Oacc[1][2*m]   += p1*v0; Oacc[1][2*m+1] += p1*v1;
      }
    }
  }
  __syncthreads();
  float l0 = 1.f / lsum[2*qp], l1 = 1.f / lsum[2*qp+1];
  size_t ob = (size_t)(b*NN + q0)*DD + h*DHH + dp*6;
  #pragma unroll
  for (int m = 0; m < 6; ++m){
    ows[ob + (size_t)(2*qp)*DD + m]   = f_bits(Oacc[0][m]*l0);
    ows[ob + (size_t)(2*qp+1)*DD + m] = f_bits(Oacc[1][m]*l1);
  }
}

// ================= output projection via MFMA + residual =================
__global__ __launch_bounds__(256, 4) void k_out(
    const unsigned short* __restrict__ ows, const float* __restrict__ enh,
    const short* __restrict__ woT, const float* __restrict__ bo, float* __restrict__ out)
{
  const int tid = threadIdx.x, blk = blockIdx.x;
  const int rt = blk / 3, ct = blk % 3;
  const int wave = tid >> 6, lane = tid & 63, quad = lane >> 4, l16 = lane & 15;
  const int row0 = rt*32;
  const int col0 = ct*256 + wave*64;
  f32x4 acc[2][4];
  #pragma unroll
  for (int rb=0;rb<2;++rb)
    #pragma unroll
    for (int cb=0;cb<4;++cb) acc[rb][cb] = (f32x4){0.f,0.f,0.f,0.f};
  for (int ks = 0; ks < 24; ++ks){
    bf16x8 af[2];
    #pragma unroll
    for (int rb=0;rb<2;++rb)
      af[rb] = *(const bf16x8*)&((const short*)ows)[(size_t)(row0 + rb*16 + l16)*DD + ks*32 + quad*8];
    #pragma unroll
    for (int cb=0;cb<4;++cb){
      bf16x8 bw = *(const bf16x8*)&woT[(size_t)(col0 + cb*16 + l16)*DD + ks*32 + quad*8];
      #pragma unroll
      for (int rb=0;rb<2;++rb)
        acc[rb][cb] = __builtin_amdgcn_mfma_f32_16x16x32_bf16(af[rb], bw, acc[rb][cb], 0,0,0);
    }
  }
  #pragma unroll
  for (int cb=0;cb<4;++cb){
    int col = col0 + cb*16 + l16;
    float bb = bo[col];
    #pragma unroll
    for (int rb=0;rb<2;++rb){
      #pragma unroll
      for (int r=0;r<4;++r){
        size_t idx = (size_t)(row0 + rb*16 + quad*4 + r)*DD + col;
        out[idx] = enh[idx] + 0.5f*(acc[rb][cb][r] + bb);
      }
    }
  }
}

extern "C" void kernel_launch(void* const* d_in, const int* in_sizes, int n_in,
                              void* d_out, int out_size, void* d_ws, size_t ws_size,
                              hipStream_t stream) {
  const float* coord = (const float*)d_in[0];
  const float* feat  = (const float*)d_in[1];
  const int*   lab   = (const int*)d_in[2];
  const float* ge_w1 = (const float*)d_in[3];
  const float* ge_b1 = (const float*)d_in[4];
  const float* ge_g1 = (const float*)d_in[5];
  const float* ge_be1= (const float*)d_in[6];
  const float* ge_w2 = (const float*)d_in[7];
  const float* ge_b2 = (const float*)d_in[8];
  const float* ge_g2 = (const float*)d_in[9];
  const float* ge_be2= (const float*)d_in[10];
  const float* ag_w1 = (const float*)d_in[11];
  const float* ag_b1 = (const float*)d_in[12];
  const float* ag_g1 = (const float*)d_in[13];
  const float* ag_be1= (const float*)d_in[14];
  const float* ag_w2 = (const float*)d_in[15];
  const float* ag_b2 = (const float*)d_in[16];
  const float* ag_g2 = (const float*)d_in[17];
  const float* ag_be2= (const float*)d_in[18];
  const float* wq = (const float*)d_in[19];
  const float* bq = (const float*)d_in[20];
  const float* wk = (const float*)d_in[21];
  const float* bk = (const float*)d_in[22];
  const float* wv = (const float*)d_in[23];
  const float* bv = (const float*)d_in[24];
  const float* wo = (const float*)d_in[25];
  const float* bo = (const float*)d_in[26];

  // Workspace 15,906,048 B. gv|mf|mg|cntw are contiguous -> single zero range.
  char* w = (char*)d_ws;
  unsigned short* geo_bf = (unsigned short*)(w);              // 1,179,648  [ow overlay]
  float*          enh_f  = (float*)(w + 1179648);             // 2,359,296
  unsigned short* enh_bf = (unsigned short*)(w + 3538944);    // 1,179,648
  unsigned short* qw_bf  = (unsigned short*)(w + 4718592);    // 1,179,648
  unsigned short* kw_bf  = (unsigned short*)(w + 5898240);    // 1,179,648
  unsigned short* vw_bf  = (unsigned short*)(w + 7077888);    // 1,179,648
  float*          gv     = (float*)(w + 8257536);             //   798,720
  float*          mf     = (float*)(w + 9056256);             //   393,216
  float*          mg     = (float*)(w + 9449472);             //   393,216
  float*          cntw   = (float*)(w + 9842688);             //       512
  float*          comb   = (float*)(w + 9843200);             //   393,216
  short*          w2T    = (short*)(w + 10236416);            //   393,216
  short*          w2r    = (short*)(w + 10629632);            //   393,216
  short*          w1t    = (short*)(w + 11022848);            //    16,384
  short*          Gm     = (short*)(w + 11039232);            //   147,456
  float*          g1s    = (float*)(w + 11186688);            //       512
  float*          gscal  = (float*)(w + 11187200);            //       256
  short*          wqT    = (short*)(w + 11187456);            // 1,179,648
  short*          wkT    = (short*)(w + 12367104);            // 1,179,648
  short*          wvT    = (short*)(w + 13546752);            // 1,179,648
  short*          woT    = (short*)(w + 14726400);            // 1,179,648
  unsigned short* ow_bf  = geo_bf;

  hipLaunchKernelGGL(k_prep,    dim3(2973),  dim3(256), 0, stream,
                     ge_w2, ge_w1, wq, wk, wv, wo,
                     gv, w2T, w2r, wqT, wkT, wvT, woT, w1t);
  hipLaunchKernelGGL(k_gprep,   dim3(258),   dim3(256), 0, stream,
                     w2T, ge_b2, w1t, ge_b1, Gm, gscal, g1s);
  hipLaunchKernelGGL(k_geo,     dim3(4608),  dim3(256), 0, stream,
                     coord, w1t, ge_b1, ge_g1, ge_be1, Gm, gscal, g1s, gv);
  hipLaunchKernelGGL(k_geofin,  dim3(768),   dim3(256), 0, stream,
                     gv, w2r, ge_b2, ge_g2, ge_be2, geo_bf);
  hipLaunchKernelGGL(k_scat,    dim3(768),   dim3(256), 0, stream,
                     lab, feat, geo_bf, mf, mg, cntw);
  hipLaunchKernelGGL(k_agg,     dim3(128),   dim3(256), 0, stream,
                     mf, mg, cntw, ag_w1, ag_b1, ag_g1, ag_be1, ag_w2, ag_b2, ag_g2, ag_be2, comb);
  hipLaunchKernelGGL(k_enhance, dim3(2304),  dim3(256), 0, stream,
                     feat, lab, cntw, comb, enh_f, enh_bf);
  hipLaunchKernelGGL(k_qkv,     dim3(216),   dim3(256), 0, stream,
                     enh_bf, geo_bf, wqT, wkT, wvT, bq, bk, bv, qw_bf, kw_bf, vw_bf);
  hipLaunchKernelGGL(k_attn,    dim3(192),   dim3(256), 0, stream,
                     qw_bf, kw_bf, vw_bf, ow_bf);
  hipLaunchKernelGGL(k_out,     dim3(72),    dim3(256), 0, stream,
                     ow_bf, enh_f, woT, bo, (float*)d_out);
}

// Round 11
// 440.895 us; speedup vs baseline: 1.9338x; 1.2485x over previous
//
#include <hip/hip_runtime.h>
#include <hip/hip_bf16.h>
#include <stdint.h>
#include <stddef.h>

#define BB 2
#define NN 384
#define DD 768
#define HH 256
#define SS 64
#define NHH 8
#define DHH 96

typedef __attribute__((ext_vector_type(8))) short bf16x8;
typedef __attribute__((ext_vector_type(4))) float f32x4;

__device__ __forceinline__ float bits_f(unsigned short u){
  unsigned x = ((unsigned)u) << 16; float f; __builtin_memcpy(&f, &x, 4); return f;
}
__device__ __forceinline__ unsigned short f_bits(float a){
  unsigned x; __builtin_memcpy(&x, &a, 4);
  unsigned r = x + 0x7fffu + ((x >> 16) & 1u);
  return (unsigned short)(r >> 16);
}
__device__ __forceinline__ float lo_f(unsigned u){ unsigned x = u << 16; float f; __builtin_memcpy(&f,&x,4); return f; }
__device__ __forceinline__ float hi_f(unsigned u){ unsigned x = u & 0xffff0000u; float f; __builtin_memcpy(&f,&x,4); return f; }

// ================= prep: zeroing + all transposes (LDS-tiled, coalesced) =================
// jobs: [0,1549) zero | [1549,1597) w2T | [1597,2365) w2r | [2365,2941) attn T |
//       [2941,2973) w1t | [2973,3021) agw1T | [3021,3069) agw2T
__global__ __launch_bounds__(256) void k_prep(
    const float* __restrict__ w2, const float* __restrict__ w1g,
    const float* __restrict__ wq, const float* __restrict__ wk,
    const float* __restrict__ wv, const float* __restrict__ wo,
    const float* __restrict__ aw1, const float* __restrict__ aw2,
    float* __restrict__ zf, short* __restrict__ w2T, short* __restrict__ w2r,
    short* __restrict__ wqT, short* __restrict__ wkT, short* __restrict__ wvT,
    short* __restrict__ woT, short* __restrict__ w1t,
    short* __restrict__ agw1T, short* __restrict__ agw2T)
{
  __shared__ short tile[64*66];
  const int tid = threadIdx.x, blk = blockIdx.x;
  if (blk < 1549){
    int idx = blk*256 + tid;
    if (idx < 396416) zf[idx] = 0.f;
    return;
  }
  if (blk < 1597){            // w2 [256,768] -> w2T [768,256]
    int t = blk - 1549;
    int r0 = (t/12)*64, c0 = (t%12)*64;
    int g = tid >> 6, c = tid & 63;
    #pragma unroll
    for (int i=0;i<16;++i){
      int r = i*4 + g;
      tile[r*66 + c] = (short)f_bits(w2[(size_t)(r0+r)*768 + c0 + c]);
    }
    __syncthreads();
    #pragma unroll
    for (int i=0;i<16;++i){
      int cc = i*4 + g, rr = c;
      w2T[(size_t)(c0+cc)*256 + r0 + rr] = tile[rr*66 + cc];
    }
    return;
  }
  if (blk < 2365){            // w2r: row-major bf16 copy
    int idx = (blk-1597)*256 + tid;
    w2r[idx] = (short)f_bits(w2[idx]);
    return;
  }
  if (blk < 2941){            // attn weights [768,768] -> T[n][k]
    int t = blk - 2365;
    int mat = t / 144, tt = t % 144;
    const float* W = (mat==0)?wq:(mat==1)?wk:(mat==2)?wv:wo;
    short* T = (mat==0)?wqT:(mat==1)?wkT:(mat==2)?wvT:woT;
    int r0 = (tt/12)*64, c0 = (tt%12)*64;
    int g = tid >> 6, c = tid & 63;
    #pragma unroll
    for (int i=0;i<16;++i){
      int r = i*4 + g;
      tile[r*66 + c] = (short)f_bits(W[(size_t)(r0+r)*768 + c0 + c]);
    }
    __syncthreads();
    #pragma unroll
    for (int i=0;i<16;++i){
      int cc = i*4 + g, rr = c;
      T[(size_t)(c0+cc)*768 + r0 + rr] = tile[rr*66 + cc];
    }
    return;
  }
  if (blk < 2973){            // w1t [256c][32k], K padded
    int idx = (blk-2941)*256 + tid;
    int c = idx >> 5, kk = idx & 31;
    w1t[idx] = (kk < 9) ? (short)f_bits(w1g[kk*256 + c]) : (short)0;
    return;
  }
  if (blk < 3021){            // ag_w1 [768,256] -> agw1T [256n][768k]
    int t = blk - 2973;
    int r0 = (t/4)*64, c0 = (t%4)*64;
    int g = tid >> 6, c = tid & 63;
    #pragma unroll
    for (int i=0;i<16;++i){
      int r = i*4 + g;
      tile[r*66 + c] = (short)f_bits(aw1[(size_t)(r0+r)*256 + c0 + c]);
    }
    __syncthreads();
    #pragma unroll
    for (int i=0;i<16;++i){
      int cc = i*4 + g, rr = c;
      agw1T[(size_t)(c0+cc)*768 + r0 + rr] = tile[rr*66 + cc];
    }
    return;
  }
  {                           // ag_w2 [256,768] -> agw2T [768n][256k]
    int t = blk - 3021;
    int r0 = (t/12)*64, c0 = (t%12)*64;
    int g = tid >> 6, c = tid & 63;
    #pragma unroll
    for (int i=0;i<16;++i){
      int r = i*4 + g;
      tile[r*66 + c] = (short)f_bits(aw2[(size_t)(r0+r)*768 + c0 + c]);
    }
    __syncthreads();
    #pragma unroll
    for (int i=0;i<16;++i){
      int cc = i*4 + g, rr = c;
      agw2T[(size_t)(c0+cc)*256 + r0 + rr] = tile[rr*66 + cc];
    }
  }
}

// ================= Gram prep v2: G via MFMA on w2r; s1/wb row-streamed =================
// grid 66: [0,64) G tiles (4 waves/blk, 1 tile/wave); 64: s1/wb/gscal; 65: g1s
__global__ __launch_bounds__(256) void k_gprep(const short* __restrict__ w2r,
                                               const float* __restrict__ b2,
                                               const short* __restrict__ w1t,
                                               const float* __restrict__ b1,
                                               short* __restrict__ Gm, float* __restrict__ gscal,
                                               float* __restrict__ g1s){
  __shared__ float b2s[768];
  __shared__ float red[8];
  const int tid = threadIdx.x, blk = blockIdx.x;
  if (blk < 64){
    const int wave = tid >> 6, lane = tid & 63, quad = lane >> 4, l16 = lane & 15;
    const int id = blk*4 + wave, ti = id >> 4, tj = id & 15;
    f32x4 acc = (f32x4){0.f,0.f,0.f,0.f};
    for (int ks = 0; ks < 24; ++ks){
      bf16x8 af = *(const bf16x8*)&w2r[(size_t)(ti*16 + l16)*768 + ks*32 + quad*8];
      bf16x8 bf = *(const bf16x8*)&w2r[(size_t)(tj*16 + l16)*768 + ks*32 + quad*8];
      acc = __builtin_amdgcn_mfma_f32_16x16x32_bf16(af, bf, acc, 0,0,0);
    }
    #pragma unroll
    for (int r = 0; r < 4; ++r)
      Gm[(ti*16 + quad*4 + r)*256 + tj*16 + l16] = (short)f_bits(acc[r]);
  } else if (blk == 64){
    for (int c = tid; c < 768; c += 256) b2s[c] = b2[c];
    __syncthreads();
    float sa = 0.f, wa = 0.f;
    const uint4* wr = (const uint4*)(w2r + (size_t)tid*768);
    #pragma unroll 4
    for (int kk = 0; kk < 96; ++kk){
      uint4 ww = wr[kk];
      const float* bp = &b2s[kk*8];
      float x0=lo_f(ww.x), x1=hi_f(ww.x), x2=lo_f(ww.y), x3=hi_f(ww.y);
      float x4=lo_f(ww.z), x5=hi_f(ww.z), x6=lo_f(ww.w), x7=hi_f(ww.w);
      sa += (x0+x1)+(x2+x3)+(x4+x5)+(x6+x7);
      wa += bp[0]*x0 + bp[1]*x1 + bp[2]*x2 + bp[3]*x3
          + bp[4]*x4 + bp[5]*x5 + bp[6]*x6 + bp[7]*x7;
    }
    Gm[256*256 + tid] = (short)f_bits(sa);
    Gm[257*256 + tid] = (short)f_bits(wa);
    #pragma unroll
    for (int rr = 258; rr < 288; ++rr) Gm[rr*256 + tid] = 0;
    float pb = 0.f, pbb = 0.f;
    for (int c = tid; c < 768; c += 256){ float bb = b2s[c]; pb += bb; pbb += bb*bb; }
    for (int m = 32; m >= 1; m >>= 1){ pb += __shfl_xor(pb,m); pbb += __shfl_xor(pbb,m); }
    if ((tid & 63) == 0){ red[tid>>6] = pb; red[4+(tid>>6)] = pbb; }
    __syncthreads();
    if (tid == 0){ gscal[0] = red[0]+red[1]+red[2]+red[3]; gscal[1] = red[4]+red[5]+red[6]+red[7]; }
  } else {
    // g1s[0..8]=s1a, [9..17]=w1b1, [18..98]=G1(9x9), [99]=Sb1, [100]=Sb1b
    const unsigned short* w1u = (const unsigned short*)w1t;
    if (tid < 81){
      int i = tid / 9, j = tid % 9;
      float acc = 0.f;
      for (int c = 0; c < 256; ++c)
        acc += bits_f(w1u[c*32 + i]) * bits_f(w1u[c*32 + j]);
      g1s[18 + tid] = acc;
    } else if (tid < 90){
      int i = tid - 81;
      float sa = 0.f, sb = 0.f;
      for (int c = 0; c < 256; ++c){
        float x = bits_f(w1u[c*32 + i]);
        sa += x; sb += x * b1[c];
      }
      g1s[i] = sa; g1s[9 + i] = sb;
    } else if (tid == 90){
      float pb = 0.f, pbb = 0.f;
      for (int c = 0; c < 256; ++c){ float bb = b1[c]; pb += bb; pbb += bb*bb; }
      g1s[99] = pb; g1s[100] = pbb;
    }
  }
}

// ================= geometric encoder; WG=(pair,jt), 256 thr, 4 waves, 3 WG/CU =================
__global__ __launch_bounds__(256, 3) void k_geo(
    const float* __restrict__ coord, const short* __restrict__ w1t,
    const float* __restrict__ b1g, const float* __restrict__ g1g, const float* __restrict__ be1g,
    const short* __restrict__ Gm, const float* __restrict__ gscal,
    const float* __restrict__ g1s, float* __restrict__ gv)
{
  __shared__ short relbf[64*36];
  __shared__ short h_bf[64*256];   // chunk-swizzled: phys_chunk=((col>>3)+row)&31
  __shared__ float rmean[64], rrstd[64];
  __shared__ float msum[64], wbsum[64], qsum[64];

  const int tid = threadIdx.x;
  const int pair = blockIdx.x % 768;
  const int jt   = blockIdx.x / 768;
  const int j0 = jt * 64;
  const int b = pair / NN;

  if (tid < 64){
    int j = j0 + tid;
    float cix = coord[pair*3+0], ciy = coord[pair*3+1], ciz = coord[pair*3+2];
    float dx = cix - coord[(b*NN+j)*3+0];
    float dy = ciy - coord[(b*NN+j)*3+1];
    float dz = ciz - coord[(b*NN+j)*3+2];
    float dist = sqrtf(dx*dx + dy*dy + dz*dz);
    float inv = 1.f / fmaxf(dist, 1e-12f);
    float x = dx*inv, y = dy*inv, z = dz*inv;
    float rv[9];
    rv[0]=dist; rv[1]=x; rv[2]=y; rv[3]=z; rv[4]=0.f; rv[5]=0.f;
    rv[6]=y*z; rv[7]=x*y; rv[8]=x*z;
    short* rr = &relbf[tid*36];
    float rbf[9];
    #pragma unroll
    for (int k=0;k<9;++k){
      unsigned short hb = f_bits(rv[k]);
      rr[k] = (short)hb; rbf[k] = bits_f(hb);
    }
    #pragma unroll
    for (int k=9;k<32;++k) rr[k]=0;
    float s = g1s[99], ssq = g1s[100];
    #pragma unroll
    for (int i=0;i<9;++i){
      s += rbf[i]*g1s[i];
      ssq += 2.f*rbf[i]*g1s[9+i];
      #pragma unroll
      for (int jj=0;jj<9;++jj) ssq += rbf[i]*rbf[jj]*g1s[18+i*9+jj];
    }
    float mean = s*(1.f/256.f);
    float var  = ssq*(1.f/256.f) - mean*mean;
    rmean[tid] = mean; rrstd[tid] = rsqrtf(var + 1e-5f);
  } else if (tid < 128){
    qsum[tid-64] = 0.f;
  }
  __syncthreads();

  const int wave = tid >> 6, lane = tid & 63, quad = lane >> 4, l16 = lane & 15;

  // ---- phase 2: MFMA mm1 + in-register LN1/ReLU -> h_bf
  {
    bf16x8 af[4];
    #pragma unroll
    for (int rb=0;rb<4;++rb)
      af[rb] = *(const bf16x8*)&relbf[(rb*16 + l16)*36 + quad*8];
    f32x4 hacc[4][4];
    #pragma unroll
    for (int ci=0;ci<4;++ci){
      int cb = wave*4 + ci;
      bf16x8 bfw = *(const bf16x8*)&w1t[(cb*16 + l16)*32 + quad*8];
      #pragma unroll
      for (int rb=0;rb<4;++rb)
        hacc[ci][rb] = __builtin_amdgcn_mfma_f32_16x16x32_bf16(af[rb], bfw, (f32x4){0.f,0.f,0.f,0.f}, 0,0,0);
    }
    f32x4 rmv[4], rsv[4];
    #pragma unroll
    for (int rb=0;rb<4;++rb){
      rmv[rb] = *(const f32x4*)&rmean[rb*16 + quad*4];
      rsv[rb] = *(const f32x4*)&rrstd[rb*16 + quad*4];
    }
    #pragma unroll
    for (int ci=0;ci<4;++ci){
      int col = (wave*4+ci)*16 + l16;
      float b1c = b1g[col], g1c = g1g[col], be1c = be1g[col];
      int chb = col >> 3, lo = col & 7;
      #pragma unroll
      for (int rb=0;rb<4;++rb){
        #pragma unroll
        for (int r=0;r<4;++r){
          int row = rb*16 + quad*4 + r;
          float hn = (hacc[ci][rb][r] + b1c - rmv[rb][r]) * rsv[rb][r] * g1c + be1c;
          h_bf[row*256 + ((chb + row)&31)*8 + lo] = (short)f_bits(fmaxf(hn, 0.f));
        }
      }
    }
  }
  __syncthreads();

  // ---- phase 3: U = H@Gm_ext; wave0 ext tile -> msum/wbsum; Q_j = sum U.h
  {
    f32x4 acc[4][4];
    #pragma unroll
    for (int ci=0;ci<4;++ci)
      #pragma unroll
      for (int rb=0;rb<4;++rb) acc[ci][rb] = (f32x4){0.f,0.f,0.f,0.f};
    f32x4 eacc[4];
    #pragma unroll
    for (int rb=0;rb<4;++rb) eacc[rb] = (f32x4){0.f,0.f,0.f,0.f};
    for (int ks=0;ks<8;++ks){
      bf16x8 a4[4];
      #pragma unroll
      for (int rb=0;rb<4;++rb){
        int row = rb*16 + l16;
        a4[rb] = *(const bf16x8*)&h_bf[row*256 + (((ks*4 + quad) + row)&31)*8];
      }
      #pragma unroll
      for (int ci=0;ci<4;++ci){
        int n = (wave*4+ci)*16 + l16;
        bf16x8 bg = *(const bf16x8*)&Gm[n*256 + ks*32 + quad*8];
        #pragma unroll
        for (int rb=0;rb<4;++rb)
          acc[ci][rb] = __builtin_amdgcn_mfma_f32_16x16x32_bf16(a4[rb], bg, acc[ci][rb], 0,0,0);
      }
      if (wave == 0){
        bf16x8 bge = *(const bf16x8*)&Gm[(256 + l16)*256 + ks*32 + quad*8];
        #pragma unroll
        for (int rb=0;rb<4;++rb)
          eacc[rb] = __builtin_amdgcn_mfma_f32_16x16x32_bf16(a4[rb], bge, eacc[rb], 0,0,0);
      }
    }
    if (wave == 0 && l16 < 2){
      float* dst = (l16 == 0) ? msum : wbsum;
      #pragma unroll
      for (int rb=0;rb<4;++rb)
        #pragma unroll
        for (int r=0;r<4;++r) dst[rb*16 + quad*4 + r] = eacc[rb][r];
    }
    #pragma unroll
    for (int rb=0;rb<4;++rb){
      #pragma unroll
      for (int r=0;r<4;++r){
        int row = rb*16 + quad*4 + r;
        float qp = 0.f;
        #pragma unroll
        for (int ci=0;ci<4;++ci){
          int col = (wave*4+ci)*16 + l16;
          float hv = bits_f((unsigned short)h_bf[row*256 + (((col>>3)+row)&31)*8 + (col&7)]);
          qp += acc[ci][rb][r] * hv;
        }
        qp += __shfl_xor(qp,1);
        qp += __shfl_xor(qp,2);
        qp += __shfl_xor(qp,4);
        qp += __shfl_xor(qp,8);
        if (l16 == 0) atomicAdd(&qsum[row], qp);
      }
    }
  }
  __syncthreads();
  if (tid < 64){
    float Sb = gscal[0], Sbb = gscal[1];
    float m2 = (msum[tid] + Sb)*(1.f/768.f);
    float ssq = qsum[tid] + 2.f*wbsum[tid] + Sbb;
    float var = ssq*(1.f/768.f) - m2*m2;
    rmean[tid] = m2; rrstd[tid] = rsqrtf(var + 1e-5f);
  }
  __syncthreads();
  if (tid < 64){
    float rr = rrstd[tid], tt = rmean[tid]*rrstd[tid];
    for (int m = 32; m >= 1; m >>= 1){ rr += __shfl_xor(rr,m); tt += __shfl_xor(tt,m); }
    if (tid == 0){
      atomicAdd(&gv[pair*260 + 256], rr);
      atomicAdd(&gv[pair*260 + 257], tt);
    }
  }
  {
    int col = tid, chb = col >> 3, lo = col & 7;
    float v = 0.f;
    #pragma unroll 8
    for (int j = 0; j < 64; ++j)
      v += rrstd[j] * bits_f((unsigned short)h_bf[j*256 + ((chb + j)&31)*8 + lo]);
    atomicAdd(&gv[pair*260 + col], v);
  }
}

// ================= finalize geo (coalesced w2r reads) =================
__global__ __launch_bounds__(256) void k_geofin(
    const float* __restrict__ gv, const short* __restrict__ w2r,
    const float* __restrict__ b2g, const float* __restrict__ g2g,
    const float* __restrict__ be2g, unsigned short* __restrict__ geo){
  __shared__ float V[256];
  __shared__ float RT[2];
  const int tid = threadIdx.x, pair = blockIdx.x;
  V[tid] = gv[pair*260 + tid];
  if (tid < 2) RT[tid] = gv[pair*260 + 256 + tid];
  __syncthreads();
  float R = RT[0], T = RT[1];
  const unsigned short* wr = (const unsigned short*)w2r;
  float a0 = 0.f, a1 = 0.f, a2 = 0.f;
  #pragma unroll 4
  for (int k = 0; k < 256; ++k){
    float vk = V[k];
    const unsigned short* row = wr + (size_t)k*768;
    a0 += vk * bits_f(row[tid]);
    a1 += vk * bits_f(row[tid+256]);
    a2 += vk * bits_f(row[tid+512]);
  }
  size_t base = (size_t)pair*DD;
  geo[base + tid]       = f_bits(g2g[tid]    *(a0 + b2g[tid]    *R - T)*(1.f/384.f) + be2g[tid]);
  geo[base + tid + 256] = f_bits(g2g[tid+256]*(a1 + b2g[tid+256]*R - T)*(1.f/384.f) + be2g[tid+256]);
  geo[base + tid + 512] = f_bits(g2g[tid+512]*(a2 + b2g[tid+512]*R - T)*(1.f/384.f) + be2g[tid+512]);
}

// ================= per-point scatter (atomics) =================
__global__ __launch_bounds__(256) void k_scat(
    const int* __restrict__ lab, const float* __restrict__ feat,
    const unsigned short* __restrict__ geo,
    float* __restrict__ mf, float* __restrict__ mg, float* __restrict__ cntw)
{
  const int tid = threadIdx.x, bn = blockIdx.x;
  const int b = bn / NN;
  const int s = lab[bn];
  const size_t base = (size_t)(b*SS + s)*DD;
  if (tid == 0) atomicAdd(&cntw[b*SS + s], 1.0f);
  #pragma unroll
  for (int u = 0; u < 3; ++u){
    int c = tid + 256*u;
    atomicAdd(&mf[base + c], feat[(size_t)bn*DD + c]);
    atomicAdd(&mg[base + c], bits_f(geo[(size_t)bn*DD + c]));
  }
}

// ================= aggregator MLP v2: bf16 transposed weights, contiguous streams =================
__global__ __launch_bounds__(256) void k_agg(
    const float* __restrict__ mf, const float* __restrict__ mg,
    const float* __restrict__ cntw,
    const short* __restrict__ w1T, const float* __restrict__ b1g,
    const float* __restrict__ g1g, const float* __restrict__ be1g,
    const short* __restrict__ w2T, const float* __restrict__ b2g,
    const float* __restrict__ g2g, const float* __restrict__ be2g,
    float* __restrict__ comb)
{
  __shared__ float xr[DD];
  __shared__ float hr[HH];
  __shared__ float red[8];
  const int tid = threadIdx.x;
  const size_t base = (size_t)blockIdx.x * DD;
  const float inv = 1.f / fmaxf(cntw[blockIdx.x], 1.f);
  for (int c = tid; c < DD; c += 256) xr[c] = mf[base + c]*inv;
  __syncthreads();
  float a = b1g[tid];
  {
    const uint4* wr = (const uint4*)(w1T + (size_t)tid*768);
    #pragma unroll 4
    for (int kk = 0; kk < 96; ++kk){
      uint4 ww = wr[kk];
      const float* xp = &xr[kk*8];
      a += xp[0]*lo_f(ww.x) + xp[1]*hi_f(ww.x)
         + xp[2]*lo_f(ww.y) + xp[3]*hi_f(ww.y)
         + xp[4]*lo_f(ww.z) + xp[5]*hi_f(ww.z)
         + xp[6]*lo_f(ww.w) + xp[7]*hi_f(ww.w);
    }
  }
  float s = a, q = a*a;
  for (int m = 32; m >= 1; m >>= 1){ s += __shfl_xor(s,m); q += __shfl_xor(q,m); }
  if ((tid & 63) == 0){ red[tid>>6] = s; red[4+(tid>>6)] = q; }
  __syncthreads();
  s = red[0]+red[1]+red[2]+red[3]; q = red[4]+red[5]+red[6]+red[7];
  float mean = s*(1.f/HH), var = q*(1.f/HH) - mean*mean, rstd = rsqrtf(var + 1e-5f);
  float h = fmaxf((a-mean)*rstd*g1g[tid] + be1g[tid], 0.f);
  hr[tid] = h;
  __syncthreads();
  float a2[3];
  #pragma unroll
  for (int u = 0; u < 3; ++u){
    int c = tid + 256*u;
    float t = b2g[c];
    const uint4* wr = (const uint4*)(w2T + (size_t)c*256);
    #pragma unroll 4
    for (int kk = 0; kk < 32; ++kk){
      uint4 ww = wr[kk];
      const float* hp = &hr[kk*8];
      t += hp[0]*lo_f(ww.x) + hp[1]*hi_f(ww.x)
         + hp[2]*lo_f(ww.y) + hp[3]*hi_f(ww.y)
         + hp[4]*lo_f(ww.z) + hp[5]*hi_f(ww.z)
         + hp[6]*lo_f(ww.w) + hp[7]*hi_f(ww.w);
    }
    a2[u] = t;
  }
  float s2 = a2[0]+a2[1]+a2[2], q2 = a2[0]*a2[0]+a2[1]*a2[1]+a2[2]*a2[2];
  for (int m = 32; m >= 1; m >>= 1){ s2 += __shfl_xor(s2,m); q2 += __shfl_xor(q2,m); }
  __syncthreads();
  if ((tid & 63) == 0){ red[tid>>6] = s2; red[4+(tid>>6)] = q2; }
  __syncthreads();
  s2 = red[0]+red[1]+red[2]+red[3]; q2 = red[4]+red[5]+red[6]+red[7];
  float mean2 = s2*(1.f/DD), rstd2 = rsqrtf(q2*(1.f/DD) - mean2*mean2 + 1e-5f);
  #pragma unroll
  for (int u = 0; u < 3; ++u){
    int c = tid + 256*u;
    comb[base + c] = (a2[u]-mean2)*rstd2*g2g[c] + be2g[c] + mg[base + c]*inv;
  }
}

// ================= gather + enhanced (fp32 + bf16 out) =================
__global__ void k_enhance(const float* __restrict__ feat, const int* __restrict__ lab,
                          const float* __restrict__ cntw, const float* __restrict__ comb,
                          float* __restrict__ enh, unsigned short* __restrict__ enhb)
{
  int idx = blockIdx.x * 256 + threadIdx.x;
  int c = idx % DD; int bn = idx / DD; int b = bn / NN;
  int l = lab[bn];
  float f = feat[idx];
  float cg = comb[(size_t)(b*SS + l)*DD + c];
  float cnt = cntw[b*SS + l];
  float e = (cnt >= 2.0f) ? (0.7f*f + 0.3f*cg) : f;
  enh[idx] = e;
  enhb[idx] = f_bits(e);
}

// ================= q/k/v projections via MFMA =================
__global__ __launch_bounds__(256, 4) void k_qkv(
    const unsigned short* __restrict__ enhb, const unsigned short* __restrict__ geo,
    const short* __restrict__ wqT, const short* __restrict__ wkT, const short* __restrict__ wvT,
    const float* __restrict__ bq, const float* __restrict__ bk, const float* __restrict__ bv,
    unsigned short* __restrict__ qo, unsigned short* __restrict__ ko, unsigned short* __restrict__ vo)
{
  const int tid = threadIdx.x, blk = blockIdx.x;
  const int m = blk / 72, rem = blk % 72;
  const int rt = rem / 3, ct = rem % 3;
  const int wave = tid >> 6, lane = tid & 63, quad = lane >> 4, l16 = lane & 15;
  const short* WT = (m==0)?wqT:(m==1)?wkT:wvT;
  const float* Bv = (m==0)?bq:(m==1)?bk:bv;
  unsigned short* Y = (m==0)?qo:(m==1)?ko:vo;
  const short* X = (const short*)((m==0)? enhb : geo);
  const float oscale = (m==0)? 0.10206207261596577f : 1.0f;
  const int row0 = rt*32;
  const int col0 = ct*256 + wave*64;

  f32x4 acc[2][4];
  #pragma unroll
  for (int rb=0;rb<2;++rb)
    #pragma unroll
    for (int cb=0;cb<4;++cb) acc[rb][cb] = (f32x4){0.f,0.f,0.f,0.f};

  for (int ks = 0; ks < 24; ++ks){
    bf16x8 af[2];
    #pragma unroll
    for (int rb=0;rb<2;++rb)
      af[rb] = *(const bf16x8*)&X[(size_t)(row0 + rb*16 + l16)*DD + ks*32 + quad*8];
    #pragma unroll
    for (int cb=0;cb<4;++cb){
      bf16x8 bw = *(const bf16x8*)&WT[(size_t)(col0 + cb*16 + l16)*DD + ks*32 + quad*8];
      #pragma unroll
      for (int rb=0;rb<2;++rb)
        acc[rb][cb] = __builtin_amdgcn_mfma_f32_16x16x32_bf16(af[rb], bw, acc[rb][cb], 0,0,0);
    }
  }
  #pragma unroll
  for (int cb=0;cb<4;++cb){
    int col = col0 + cb*16 + l16;
    float bb = Bv[col];
    #pragma unroll
    for (int rb=0;rb<2;++rb){
      #pragma unroll
      for (int r=0;r<4;++r){
        int row = row0 + rb*16 + quad*4 + r;
        Y[(size_t)row*DD + col] = f_bits((acc[rb][cb][r] + bb)*oscale);
      }
    }
  }
}

// ================= attention =================
__global__ __launch_bounds__(256) void k_attn(
    const unsigned short* __restrict__ qws, const unsigned short* __restrict__ kws,
    const unsigned short* __restrict__ vws, unsigned short* __restrict__ ows)
{
  __shared__ short kt[64*104];
  __shared__ short vt[64*104];
  __shared__ float st[32*66];
  __shared__ float lsum[32];
  const int tid = threadIdx.x;
  const int blk = blockIdx.x;
  const int b = blk / (NHH*12); int rem = blk % (NHH*12);
  const int h = rem / 12; const int qt = rem % 12; const int q0 = qt*32;
  const int sq = tid >> 3, jp = tid & 7;
  const int qp = tid >> 4, dp = tid & 15;
  unsigned qreg[48];
  {
    const unsigned* qr = (const unsigned*)(qws + (size_t)(b*NN + q0 + sq)*DD + h*DHH);
    #pragma unroll
    for (int d2 = 0; d2 < 48; ++d2) qreg[d2] = qr[d2];
  }
  if (tid < 32) lsum[tid] = 0.f;
  float Oacc[2][6];
  #pragma unroll
  for (int a = 0; a < 2; ++a)
    #pragma unroll
    for (int m = 0; m < 6; ++m) Oacc[a][m] = 0.f;

  for (int jt = 0; jt < 6; ++jt){
    const int j0 = jt * 64;
    __syncthreads();
    for (int x = tid; x < 64*48; x += 256){
      int jl = x / 48, du = x % 48;
      size_t rowoff = (size_t)(b*NN + j0 + jl)*DD + h*DHH;
      ((unsigned*)&kt[jl*104])[du] = ((const unsigned*)(kws + rowoff))[du];
      ((unsigned*)&vt[jl*104])[du] = ((const unsigned*)(vws + rowoff))[du];
    }
    __syncthreads();
    float lpart = 0.f;
    #pragma unroll
    for (int jj = 0; jj < 8; ++jj){
      int j = jp*8 + jj;
      const uint4* kr4 = (const uint4*)&kt[j*104];
      float s = 0.f;
      #pragma unroll
      for (int d4 = 0; d4 < 12; ++d4){
        uint4 kk = kr4[d4];
        unsigned q0r = qreg[4*d4], q1r = qreg[4*d4+1], q2r = qreg[4*d4+2], q3r = qreg[4*d4+3];
        s += lo_f(kk.x)*lo_f(q0r) + hi_f(kk.x)*hi_f(q0r);
        s += lo_f(kk.y)*lo_f(q1r) + hi_f(kk.y)*hi_f(q1r);
        s += lo_f(kk.z)*lo_f(q2r) + hi_f(kk.z)*hi_f(q2r);
        s += lo_f(kk.w)*lo_f(q3r) + hi_f(kk.w)*hi_f(q3r);
      }
      float p = __expf(s);
      st[sq*66 + j] = p;
      lpart += p;
    }
    lpart += __shfl_xor(lpart,1);
    lpart += __shfl_xor(lpart,2);
    lpart += __shfl_xor(lpart,4);
    if (jp == 0) lsum[sq] += lpart;
    __syncthreads();
    #pragma unroll 4
    for (int j = 0; j < 64; ++j){
      float p0 = st[(2*qp)*66 + j];
      float p1 = st[(2*qp+1)*66 + j];
      const unsigned* vr = (const unsigned*)&vt[j*104 + dp*6];
      #pragma unroll
      for (int m = 0; m < 3; ++m){
        unsigned vv = vr[m];
        float v0 = lo_f(vv), v1 = hi_f(vv);
        Oacc[0][2*m]   += p0*v0; Oacc[0][2*m+1] += p0*v1;
        Oacc[1][2*m]   += p1*v0; Oacc[1][2*m+1] += p1*v1;
      }
    }
  }
  __syncthreads();
  float l0 = 1.f / lsum[2*qp], l1 = 1.f / lsum[2*qp+1];
  size_t ob = (size_t)(b*NN + q0)*DD + h*DHH + dp*6;
  #pragma unroll
  for (int m = 0; m < 6; ++m){
    ows[ob + (size_t)(2*qp)*DD + m]   = f_bits(Oacc[0][m]*l0);
    ows[ob + (size_t)(2*qp+1)*DD + m] = f_bits(Oacc[1][m]*l1);
  }
}

// ================= output projection via MFMA + residual =================
__global__ __launch_bounds__(256, 4) void k_out(
    const unsigned short* __restrict__ ows, const float* __restrict__ enh,
    const short* __restrict__ woT, const float* __restrict__ bo, float* __restrict__ out)
{
  const int tid = threadIdx.x, blk = blockIdx.x;
  const int rt = blk / 3, ct = blk % 3;
  const int wave = tid >> 6, lane = tid & 63, quad = lane >> 4, l16 = lane & 15;
  const int row0 = rt*32;
  const int col0 = ct*256 + wave*64;
  f32x4 acc[2][4];
  #pragma unroll
  for (int rb=0;rb<2;++rb)
    #pragma unroll
    for (int cb=0;cb<4;++cb) acc[rb][cb] = (f32x4){0.f,0.f,0.f,0.f};
  for (int ks = 0; ks < 24; ++ks){
    bf16x8 af[2];
    #pragma unroll
    for (int rb=0;rb<2;++rb)
      af[rb] = *(const bf16x8*)&((const short*)ows)[(size_t)(row0 + rb*16 + l16)*DD + ks*32 + quad*8];
    #pragma unroll
    for (int cb=0;cb<4;++cb){
      bf16x8 bw = *(const bf16x8*)&woT[(size_t)(col0 + cb*16 + l16)*DD + ks*32 + quad*8];
      #pragma unroll
      for (int rb=0;rb<2;++rb)
        acc[rb][cb] = __builtin_amdgcn_mfma_f32_16x16x32_bf16(af[rb], bw, acc[rb][cb], 0,0,0);
    }
  }
  #pragma unroll
  for (int cb=0;cb<4;++cb){
    int col = col0 + cb*16 + l16;
    float bb = bo[col];
    #pragma unroll
    for (int rb=0;rb<2;++rb){
      #pragma unroll
      for (int r=0;r<4;++r){
        size_t idx = (size_t)(row0 + rb*16 + quad*4 + r)*DD + col;
        out[idx] = enh[idx] + 0.5f*(acc[rb][cb][r] + bb);
      }
    }
  }
}

extern "C" void kernel_launch(void* const* d_in, const int* in_sizes, int n_in,
                              void* d_out, int out_size, void* d_ws, size_t ws_size,
                              hipStream_t stream) {
  const float* coord = (const float*)d_in[0];
  const float* feat  = (const float*)d_in[1];
  const int*   lab   = (const int*)d_in[2];
  const float* ge_w1 = (const float*)d_in[3];
  const float* ge_b1 = (const float*)d_in[4];
  const float* ge_g1 = (const float*)d_in[5];
  const float* ge_be1= (const float*)d_in[6];
  const float* ge_w2 = (const float*)d_in[7];
  const float* ge_b2 = (const float*)d_in[8];
  const float* ge_g2 = (const float*)d_in[9];
  const float* ge_be2= (const float*)d_in[10];
  const float* ag_w1 = (const float*)d_in[11];
  const float* ag_b1 = (const float*)d_in[12];
  const float* ag_g1 = (const float*)d_in[13];
  const float* ag_be1= (const float*)d_in[14];
  const float* ag_w2 = (const float*)d_in[15];
  const float* ag_b2 = (const float*)d_in[16];
  const float* ag_g2 = (const float*)d_in[17];
  const float* ag_be2= (const float*)d_in[18];
  const float* wq = (const float*)d_in[19];
  const float* bq = (const float*)d_in[20];
  const float* wk = (const float*)d_in[21];
  const float* bk = (const float*)d_in[22];
  const float* wv = (const float*)d_in[23];
  const float* bv = (const float*)d_in[24];
  const float* wo = (const float*)d_in[25];
  const float* bo = (const float*)d_in[26];

  // Workspace 16,692,480 B. gv|mf|mg|cntw contiguous -> single zero range.
  char* w = (char*)d_ws;
  unsigned short* geo_bf = (unsigned short*)(w);              // 1,179,648  [ow overlay]
  float*          enh_f  = (float*)(w + 1179648);             // 2,359,296
  unsigned short* enh_bf = (unsigned short*)(w + 3538944);    // 1,179,648
  unsigned short* qw_bf  = (unsigned short*)(w + 4718592);    // 1,179,648
  unsigned short* kw_bf  = (unsigned short*)(w + 5898240);    // 1,179,648
  unsigned short* vw_bf  = (unsigned short*)(w + 7077888);    // 1,179,648
  float*          gv     = (float*)(w + 8257536);             //   798,720
  float*          mf     = (float*)(w + 9056256);             //   393,216
  float*          mg     = (float*)(w + 9449472);             //   393,216
  float*          cntw   = (float*)(w + 9842688);             //       512
  float*          comb   = (float*)(w + 9843200);             //   393,216
  short*          w2T    = (short*)(w + 10236416);            //   393,216
  short*          w2r    = (short*)(w + 10629632);            //   393,216
  short*          w1t    = (short*)(w + 11022848);            //    16,384
  short*          Gm     = (short*)(w + 11039232);            //   147,456
  float*          g1s    = (float*)(w + 11186688);            //       512
  float*          gscal  = (float*)(w + 11187200);            //       256
  short*          wqT    = (short*)(w + 11187456);            // 1,179,648
  short*          wkT    = (short*)(w + 12367104);            // 1,179,648
  short*          wvT    = (short*)(w + 13546752);            // 1,179,648
  short*          woT    = (short*)(w + 14726400);            // 1,179,648
  short*          agw1T  = (short*)(w + 15906048);            //   393,216
  short*          agw2T  = (short*)(w + 16299264);            //   393,216
  unsigned short* ow_bf  = geo_bf;

  hipLaunchKernelGGL(k_prep,    dim3(3069),  dim3(256), 0, stream,
                     ge_w2, ge_w1, wq, wk, wv, wo, ag_w1, ag_w2,
                     gv, w2T, w2r, wqT, wkT, wvT, woT, w1t, agw1T, agw2T);
  hipLaunchKernelGGL(k_gprep,   dim3(66),    dim3(256), 0, stream,
                     w2r, ge_b2, w1t, ge_b1, Gm, gscal, g1s);
  hipLaunchKernelGGL(k_geo,     dim3(4608),  dim3(256), 0, stream,
                     coord, w1t, ge_b1, ge_g1, ge_be1, Gm, gscal, g1s, gv);
  hipLaunchKernelGGL(k_geofin,  dim3(768),   dim3(256), 0, stream,
                     gv, w2r, ge_b2, ge_g2, ge_be2, geo_bf);
  hipLaunchKernelGGL(k_scat,    dim3(768),   dim3(256), 0, stream,
                     lab, feat, geo_bf, mf, mg, cntw);
  hipLaunchKernelGGL(k_agg,     dim3(128),   dim3(256), 0, stream,
                     mf, mg, cntw, agw1T, ag_b1, ag_g1, ag_be1, agw2T, ag_b2, ag_g2, ag_be2, comb);
  hipLaunchKernelGGL(k_enhance, dim3(2304),  dim3(256), 0, stream,
                     feat, lab, cntw, comb, enh_f, enh_bf);
  hipLaunchKernelGGL(k_qkv,     dim3(216),   dim3(256), 0, stream,
                     enh_bf, geo_bf, wqT, wkT, wvT, bq, bk, bv, qw_bf, kw_bf, vw_bf);
  hipLaunchKernelGGL(k_attn,    dim3(192),   dim3(256), 0, stream,
                     qw_bf, kw_bf, vw_bf, ow_bf);
  hipLaunchKernelGGL(k_out,     dim3(72),    dim3(256), 0, stream,
                     ow_bf, enh_f, woT, bo, (float*)d_out);
}

// Round 12
// 430.540 us; speedup vs baseline: 1.9803x; 1.0241x over previous
//
#include <hip/hip_runtime.h>
#include <hip/hip_bf16.h>
#include <stdint.h>
#include <stddef.h>

#define BB 2
#define NN 384
#define DD 768
#define HH 256
#define SS 64
#define NHH 8
#define DHH 96

typedef __attribute__((ext_vector_type(8))) short bf16x8;
typedef __attribute__((ext_vector_type(4))) float f32x4;

__device__ __forceinline__ float bits_f(unsigned short u){
  unsigned x = ((unsigned)u) << 16; float f; __builtin_memcpy(&f, &x, 4); return f;
}
__device__ __forceinline__ unsigned short f_bits(float a){
  unsigned x; __builtin_memcpy(&x, &a, 4);
  unsigned r = x + 0x7fffu + ((x >> 16) & 1u);
  return (unsigned short)(r >> 16);
}
__device__ __forceinline__ float lo_f(unsigned u){ unsigned x = u << 16; float f; __builtin_memcpy(&f,&x,4); return f; }
__device__ __forceinline__ float hi_f(unsigned u){ unsigned x = u & 0xffff0000u; float f; __builtin_memcpy(&f,&x,4); return f; }

// ================= prep: zeroing + all transposes (LDS-tiled, coalesced) =================
__global__ __launch_bounds__(256) void k_prep(
    const float* __restrict__ w2, const float* __restrict__ w1g,
    const float* __restrict__ wq, const float* __restrict__ wk,
    const float* __restrict__ wv, const float* __restrict__ wo,
    const float* __restrict__ aw1, const float* __restrict__ aw2,
    float* __restrict__ zf, short* __restrict__ w2T, short* __restrict__ w2r,
    short* __restrict__ wqT, short* __restrict__ wkT, short* __restrict__ wvT,
    short* __restrict__ woT, short* __restrict__ w1t,
    short* __restrict__ agw1T, short* __restrict__ agw2T)
{
  __shared__ short tile[64*66];
  const int tid = threadIdx.x, blk = blockIdx.x;
  if (blk < 1549){
    int idx = blk*256 + tid;
    if (idx < 396416) zf[idx] = 0.f;
    return;
  }
  if (blk < 1597){            // w2 [256,768] -> w2T [768,256]
    int t = blk - 1549;
    int r0 = (t/12)*64, c0 = (t%12)*64;
    int g = tid >> 6, c = tid & 63;
    #pragma unroll
    for (int i=0;i<16;++i){
      int r = i*4 + g;
      tile[r*66 + c] = (short)f_bits(w2[(size_t)(r0+r)*768 + c0 + c]);
    }
    __syncthreads();
    #pragma unroll
    for (int i=0;i<16;++i){
      int cc = i*4 + g, rr = c;
      w2T[(size_t)(c0+cc)*256 + r0 + rr] = tile[rr*66 + cc];
    }
    return;
  }
  if (blk < 2365){            // w2r: row-major bf16 copy
    int idx = (blk-1597)*256 + tid;
    w2r[idx] = (short)f_bits(w2[idx]);
    return;
  }
  if (blk < 2941){            // attn weights [768,768] -> T[n][k]
    int t = blk - 2365;
    int mat = t / 144, tt = t % 144;
    const float* W = (mat==0)?wq:(mat==1)?wk:(mat==2)?wv:wo;
    short* T = (mat==0)?wqT:(mat==1)?wkT:(mat==2)?wvT:woT;
    int r0 = (tt/12)*64, c0 = (tt%12)*64;
    int g = tid >> 6, c = tid & 63;
    #pragma unroll
    for (int i=0;i<16;++i){
      int r = i*4 + g;
      tile[r*66 + c] = (short)f_bits(W[(size_t)(r0+r)*768 + c0 + c]);
    }
    __syncthreads();
    #pragma unroll
    for (int i=0;i<16;++i){
      int cc = i*4 + g, rr = c;
      T[(size_t)(c0+cc)*768 + r0 + rr] = tile[rr*66 + cc];
    }
    return;
  }
  if (blk < 2973){            // w1t [256c][32k], K padded
    int idx = (blk-2941)*256 + tid;
    int c = idx >> 5, kk = idx & 31;
    w1t[idx] = (kk < 9) ? (short)f_bits(w1g[kk*256 + c]) : (short)0;
    return;
  }
  if (blk < 3021){            // ag_w1 [768,256] -> agw1T [256n][768k]
    int t = blk - 2973;
    int r0 = (t/4)*64, c0 = (t%4)*64;
    int g = tid >> 6, c = tid & 63;
    #pragma unroll
    for (int i=0;i<16;++i){
      int r = i*4 + g;
      tile[r*66 + c] = (short)f_bits(aw1[(size_t)(r0+r)*256 + c0 + c]);
    }
    __syncthreads();
    #pragma unroll
    for (int i=0;i<16;++i){
      int cc = i*4 + g, rr = c;
      agw1T[(size_t)(c0+cc)*768 + r0 + rr] = tile[rr*66 + cc];
    }
    return;
  }
  {                           // ag_w2 [256,768] -> agw2T [768n][256k]
    int t = blk - 3021;
    int r0 = (t/12)*64, c0 = (t%12)*64;
    int g = tid >> 6, c = tid & 63;
    #pragma unroll
    for (int i=0;i<16;++i){
      int r = i*4 + g;
      tile[r*66 + c] = (short)f_bits(aw2[(size_t)(r0+r)*768 + c0 + c]);
    }
    __syncthreads();
    #pragma unroll
    for (int i=0;i<16;++i){
      int cc = i*4 + g, rr = c;
      agw2T[(size_t)(c0+cc)*256 + r0 + rr] = tile[rr*66 + cc];
    }
  }
}

// ================= Gram prep v2 =================
__global__ __launch_bounds__(256) void k_gprep(const short* __restrict__ w2r,
                                               const float* __restrict__ b2,
                                               const short* __restrict__ w1t,
                                               const float* __restrict__ b1,
                                               short* __restrict__ Gm, float* __restrict__ gscal,
                                               float* __restrict__ g1s){
  __shared__ float b2s[768];
  __shared__ float red[8];
  const int tid = threadIdx.x, blk = blockIdx.x;
  if (blk < 64){
    const int wave = tid >> 6, lane = tid & 63, quad = lane >> 4, l16 = lane & 15;
    const int id = blk*4 + wave, ti = id >> 4, tj = id & 15;
    f32x4 acc = (f32x4){0.f,0.f,0.f,0.f};
    for (int ks = 0; ks < 24; ++ks){
      bf16x8 af = *(const bf16x8*)&w2r[(size_t)(ti*16 + l16)*768 + ks*32 + quad*8];
      bf16x8 bf = *(const bf16x8*)&w2r[(size_t)(tj*16 + l16)*768 + ks*32 + quad*8];
      acc = __builtin_amdgcn_mfma_f32_16x16x32_bf16(af, bf, acc, 0,0,0);
    }
    #pragma unroll
    for (int r = 0; r < 4; ++r)
      Gm[(ti*16 + quad*4 + r)*256 + tj*16 + l16] = (short)f_bits(acc[r]);
  } else if (blk == 64){
    for (int c = tid; c < 768; c += 256) b2s[c] = b2[c];
    __syncthreads();
    float sa = 0.f, wa = 0.f;
    const uint4* wr = (const uint4*)(w2r + (size_t)tid*768);
    #pragma unroll 4
    for (int kk = 0; kk < 96; ++kk){
      uint4 ww = wr[kk];
      const float* bp = &b2s[kk*8];
      float x0=lo_f(ww.x), x1=hi_f(ww.x), x2=lo_f(ww.y), x3=hi_f(ww.y);
      float x4=lo_f(ww.z), x5=hi_f(ww.z), x6=lo_f(ww.w), x7=hi_f(ww.w);
      sa += (x0+x1)+(x2+x3)+(x4+x5)+(x6+x7);
      wa += bp[0]*x0 + bp[1]*x1 + bp[2]*x2 + bp[3]*x3
          + bp[4]*x4 + bp[5]*x5 + bp[6]*x6 + bp[7]*x7;
    }
    Gm[256*256 + tid] = (short)f_bits(sa);
    Gm[257*256 + tid] = (short)f_bits(wa);
    #pragma unroll
    for (int rr = 258; rr < 288; ++rr) Gm[rr*256 + tid] = 0;
    float pb = 0.f, pbb = 0.f;
    for (int c = tid; c < 768; c += 256){ float bb = b2s[c]; pb += bb; pbb += bb*bb; }
    for (int m = 32; m >= 1; m >>= 1){ pb += __shfl_xor(pb,m); pbb += __shfl_xor(pbb,m); }
    if ((tid & 63) == 0){ red[tid>>6] = pb; red[4+(tid>>6)] = pbb; }
    __syncthreads();
    if (tid == 0){ gscal[0] = red[0]+red[1]+red[2]+red[3]; gscal[1] = red[4]+red[5]+red[6]+red[7]; }
  } else {
    const unsigned short* w1u = (const unsigned short*)w1t;
    if (tid < 81){
      int i = tid / 9, j = tid % 9;
      float acc = 0.f;
      for (int c = 0; c < 256; ++c)
        acc += bits_f(w1u[c*32 + i]) * bits_f(w1u[c*32 + j]);
      g1s[18 + tid] = acc;
    } else if (tid < 90){
      int i = tid - 81;
      float sa = 0.f, sb = 0.f;
      for (int c = 0; c < 256; ++c){
        float x = bits_f(w1u[c*32 + i]);
        sa += x; sb += x * b1[c];
      }
      g1s[i] = sa; g1s[9 + i] = sb;
    } else if (tid == 90){
      float pb = 0.f, pbb = 0.f;
      for (int c = 0; c < 256; ++c){ float bb = b1[c]; pb += bb; pbb += bb*bb; }
      g1s[99] = pb; g1s[100] = pbb;
    }
  }
}

// ================= geometric encoder; WG=(pair,jt), 256 thr, 3 WG/CU =================
__global__ __launch_bounds__(256, 3) void k_geo(
    const float* __restrict__ coord, const short* __restrict__ w1t,
    const float* __restrict__ b1g, const float* __restrict__ g1g, const float* __restrict__ be1g,
    const short* __restrict__ Gm, const float* __restrict__ gscal,
    const float* __restrict__ g1s, float* __restrict__ gv)
{
  __shared__ short relbf[64*36];
  __shared__ short h_bf[64*256];   // chunk-swizzled: phys_chunk=((col>>3)+row)&31
  __shared__ float rmean[64], rrstd[64];
  __shared__ float msum[64], wbsum[64], qsum[64];

  const int tid = threadIdx.x;
  const int pair = blockIdx.x % 768;
  const int jt   = blockIdx.x / 768;
  const int j0 = jt * 64;
  const int b = pair / NN;

  if (tid < 64){
    int j = j0 + tid;
    float cix = coord[pair*3+0], ciy = coord[pair*3+1], ciz = coord[pair*3+2];
    float dx = cix - coord[(b*NN+j)*3+0];
    float dy = ciy - coord[(b*NN+j)*3+1];
    float dz = ciz - coord[(b*NN+j)*3+2];
    float dist = sqrtf(dx*dx + dy*dy + dz*dz);
    float inv = 1.f / fmaxf(dist, 1e-12f);
    float x = dx*inv, y = dy*inv, z = dz*inv;
    float rv[9];
    rv[0]=dist; rv[1]=x; rv[2]=y; rv[3]=z; rv[4]=0.f; rv[5]=0.f;
    rv[6]=y*z; rv[7]=x*y; rv[8]=x*z;
    short* rr = &relbf[tid*36];
    float rbf[9];
    #pragma unroll
    for (int k=0;k<9;++k){
      unsigned short hb = f_bits(rv[k]);
      rr[k] = (short)hb; rbf[k] = bits_f(hb);
    }
    #pragma unroll
    for (int k=9;k<32;++k) rr[k]=0;
    float s = g1s[99], ssq = g1s[100];
    #pragma unroll
    for (int i=0;i<9;++i){
      s += rbf[i]*g1s[i];
      ssq += 2.f*rbf[i]*g1s[9+i];
      #pragma unroll
      for (int jj=0;jj<9;++jj) ssq += rbf[i]*rbf[jj]*g1s[18+i*9+jj];
    }
    float mean = s*(1.f/256.f);
    float var  = ssq*(1.f/256.f) - mean*mean;
    rmean[tid] = mean; rrstd[tid] = rsqrtf(var + 1e-5f);
  } else if (tid < 128){
    qsum[tid-64] = 0.f;
  }
  __syncthreads();

  const int wave = tid >> 6, lane = tid & 63, quad = lane >> 4, l16 = lane & 15;

  // ---- phase 2: MFMA mm1 + in-register LN1/ReLU -> h_bf
  {
    bf16x8 af[4];
    #pragma unroll
    for (int rb=0;rb<4;++rb)
      af[rb] = *(const bf16x8*)&relbf[(rb*16 + l16)*36 + quad*8];
    f32x4 hacc[4][4];
    #pragma unroll
    for (int ci=0;ci<4;++ci){
      int cb = wave*4 + ci;
      bf16x8 bfw = *(const bf16x8*)&w1t[(cb*16 + l16)*32 + quad*8];
      #pragma unroll
      for (int rb=0;rb<4;++rb)
        hacc[ci][rb] = __builtin_amdgcn_mfma_f32_16x16x32_bf16(af[rb], bfw, (f32x4){0.f,0.f,0.f,0.f}, 0,0,0);
    }
    f32x4 rmv[4], rsv[4];
    #pragma unroll
    for (int rb=0;rb<4;++rb){
      rmv[rb] = *(const f32x4*)&rmean[rb*16 + quad*4];
      rsv[rb] = *(const f32x4*)&rrstd[rb*16 + quad*4];
    }
    #pragma unroll
    for (int ci=0;ci<4;++ci){
      int col = (wave*4+ci)*16 + l16;
      float b1c = b1g[col], g1c = g1g[col], be1c = be1g[col];
      int chb = col >> 3, lo = col & 7;
      #pragma unroll
      for (int rb=0;rb<4;++rb){
        #pragma unroll
        for (int r=0;r<4;++r){
          int row = rb*16 + quad*4 + r;
          float hn = (hacc[ci][rb][r] + b1c - rmv[rb][r]) * rsv[rb][r] * g1c + be1c;
          h_bf[row*256 + ((chb + row)&31)*8 + lo] = (short)f_bits(fmaxf(hn, 0.f));
        }
      }
    }
  }
  __syncthreads();

  // ---- phase 3: U = H@Gm_ext; wave0 ext tile -> msum/wbsum; Q_j = sum U.h
  {
    f32x4 acc[4][4];
    #pragma unroll
    for (int ci=0;ci<4;++ci)
      #pragma unroll
      for (int rb=0;rb<4;++rb) acc[ci][rb] = (f32x4){0.f,0.f,0.f,0.f};
    f32x4 eacc[4];
    #pragma unroll
    for (int rb=0;rb<4;++rb) eacc[rb] = (f32x4){0.f,0.f,0.f,0.f};
    for (int ks=0;ks<8;++ks){
      bf16x8 a4[4];
      #pragma unroll
      for (int rb=0;rb<4;++rb){
        int row = rb*16 + l16;
        a4[rb] = *(const bf16x8*)&h_bf[row*256 + (((ks*4 + quad) + row)&31)*8];
      }
      #pragma unroll
      for (int ci=0;ci<4;++ci){
        int n = (wave*4+ci)*16 + l16;
        bf16x8 bg = *(const bf16x8*)&Gm[n*256 + ks*32 + quad*8];
        #pragma unroll
        for (int rb=0;rb<4;++rb)
          acc[ci][rb] = __builtin_amdgcn_mfma_f32_16x16x32_bf16(a4[rb], bg, acc[ci][rb], 0,0,0);
      }
      if (wave == 0){
        bf16x8 bge = *(const bf16x8*)&Gm[(256 + l16)*256 + ks*32 + quad*8];
        #pragma unroll
        for (int rb=0;rb<4;++rb)
          eacc[rb] = __builtin_amdgcn_mfma_f32_16x16x32_bf16(a4[rb], bge, eacc[rb], 0,0,0);
      }
    }
    if (wave == 0 && l16 < 2){
      float* dst = (l16 == 0) ? msum : wbsum;
      #pragma unroll
      for (int rb=0;rb<4;++rb)
        #pragma unroll
        for (int r=0;r<4;++r) dst[rb*16 + quad*4 + r] = eacc[rb][r];
    }
    #pragma unroll
    for (int rb=0;rb<4;++rb){
      #pragma unroll
      for (int r=0;r<4;++r){
        int row = rb*16 + quad*4 + r;
        float qp = 0.f;
        #pragma unroll
        for (int ci=0;ci<4;++ci){
          int col = (wave*4+ci)*16 + l16;
          float hv = bits_f((unsigned short)h_bf[row*256 + (((col>>3)+row)&31)*8 + (col&7)]);
          qp += acc[ci][rb][r] * hv;
        }
        qp += __shfl_xor(qp,1);
        qp += __shfl_xor(qp,2);
        qp += __shfl_xor(qp,4);
        qp += __shfl_xor(qp,8);
        if (l16 == 0) atomicAdd(&qsum[row], qp);
      }
    }
  }
  __syncthreads();
  if (tid < 64){
    float Sb = gscal[0], Sbb = gscal[1];
    float m2 = (msum[tid] + Sb)*(1.f/768.f);
    float ssq = qsum[tid] + 2.f*wbsum[tid] + Sbb;
    float var = ssq*(1.f/768.f) - m2*m2;
    rmean[tid] = m2; rrstd[tid] = rsqrtf(var + 1e-5f);
  }
  __syncthreads();
  if (tid < 64){
    float rr = rrstd[tid], tt = rmean[tid]*rrstd[tid];
    for (int m = 32; m >= 1; m >>= 1){ rr += __shfl_xor(rr,m); tt += __shfl_xor(tt,m); }
    if (tid == 0){
      atomicAdd(&gv[pair*260 + 256], rr);
      atomicAdd(&gv[pair*260 + 257], tt);
    }
  }
  // ---- V = sum_j r_j h_j : vectorized b128 reads, butterfly over jg, 256 atomics/WG
  {
    const int cg = tid >> 3, jg = tid & 7;   // cg: 32 chunk groups, jg: 8 j-subsets
    float vacc[8];
    #pragma unroll
    for (int e=0;e<8;++e) vacc[e] = 0.f;
    #pragma unroll
    for (int jj = 0; jj < 8; ++jj){
      int j = jg*8 + jj;
      bf16x8 hv8 = *(const bf16x8*)&h_bf[j*256 + ((cg + j)&31)*8];
      float r = rrstd[j];
      #pragma unroll
      for (int e=0;e<8;++e) vacc[e] += r * bits_f((unsigned short)hv8[e]);
    }
    #pragma unroll
    for (int e=0;e<8;++e){
      vacc[e] += __shfl_xor(vacc[e],1);
      vacc[e] += __shfl_xor(vacc[e],2);
      vacc[e] += __shfl_xor(vacc[e],4);
    }
    if (jg == 0){
      #pragma unroll
      for (int e=0;e<8;++e) atomicAdd(&gv[pair*260 + cg*8 + e], vacc[e]);
    }
  }
}

// ================= finalize geo + scatter (fused) =================
__global__ __launch_bounds__(256) void k_geoscat(
    const float* __restrict__ gv, const short* __restrict__ w2r,
    const float* __restrict__ b2g, const float* __restrict__ g2g,
    const float* __restrict__ be2g, unsigned short* __restrict__ geo,
    const int* __restrict__ lab, const float* __restrict__ feat,
    float* __restrict__ mf, float* __restrict__ mg, float* __restrict__ cntw){
  __shared__ float V[256];
  __shared__ float RT[2];
  const int tid = threadIdx.x, pair = blockIdx.x;
  V[tid] = gv[pair*260 + tid];
  if (tid < 2) RT[tid] = gv[pair*260 + 256 + tid];
  __syncthreads();
  float R = RT[0], T = RT[1];
  const unsigned short* wr = (const unsigned short*)w2r;
  float a0 = 0.f, a1 = 0.f, a2 = 0.f;
  #pragma unroll 4
  for (int k = 0; k < 256; ++k){
    float vk = V[k];
    const unsigned short* row = wr + (size_t)k*768;
    a0 += vk * bits_f(row[tid]);
    a1 += vk * bits_f(row[tid+256]);
    a2 += vk * bits_f(row[tid+512]);
  }
  size_t base = (size_t)pair*DD;
  unsigned short r0 = f_bits(g2g[tid]    *(a0 + b2g[tid]    *R - T)*(1.f/384.f) + be2g[tid]);
  unsigned short r1 = f_bits(g2g[tid+256]*(a1 + b2g[tid+256]*R - T)*(1.f/384.f) + be2g[tid+256]);
  unsigned short r2 = f_bits(g2g[tid+512]*(a2 + b2g[tid+512]*R - T)*(1.f/384.f) + be2g[tid+512]);
  geo[base + tid]       = r0;
  geo[base + tid + 256] = r1;
  geo[base + tid + 512] = r2;
  // scatter into superpoint means
  const int b = pair / NN;
  const int s = lab[pair];
  const size_t sb = (size_t)(b*SS + s)*DD;
  if (tid == 0) atomicAdd(&cntw[b*SS + s], 1.0f);
  atomicAdd(&mf[sb + tid],       feat[base + tid]);
  atomicAdd(&mf[sb + tid + 256], feat[base + tid + 256]);
  atomicAdd(&mf[sb + tid + 512], feat[base + tid + 512]);
  atomicAdd(&mg[sb + tid],       bits_f(r0));
  atomicAdd(&mg[sb + tid + 256], bits_f(r1));
  atomicAdd(&mg[sb + tid + 512], bits_f(r2));
}

// ================= aggregator MLP v2 =================
__global__ __launch_bounds__(256) void k_agg(
    const float* __restrict__ mf, const float* __restrict__ mg,
    const float* __restrict__ cntw,
    const short* __restrict__ w1T, const float* __restrict__ b1g,
    const float* __restrict__ g1g, const float* __restrict__ be1g,
    const short* __restrict__ w2T, const float* __restrict__ b2g,
    const float* __restrict__ g2g, const float* __restrict__ be2g,
    float* __restrict__ comb)
{
  __shared__ float xr[DD];
  __shared__ float hr[HH];
  __shared__ float red[8];
  const int tid = threadIdx.x;
  const size_t base = (size_t)blockIdx.x * DD;
  const float inv = 1.f / fmaxf(cntw[blockIdx.x], 1.f);
  for (int c = tid; c < DD; c += 256) xr[c] = mf[base + c]*inv;
  __syncthreads();
  float a = b1g[tid];
  {
    const uint4* wr = (const uint4*)(w1T + (size_t)tid*768);
    #pragma unroll 4
    for (int kk = 0; kk < 96; ++kk){
      uint4 ww = wr[kk];
      const float* xp = &xr[kk*8];
      a += xp[0]*lo_f(ww.x) + xp[1]*hi_f(ww.x)
         + xp[2]*lo_f(ww.y) + xp[3]*hi_f(ww.y)
         + xp[4]*lo_f(ww.z) + xp[5]*hi_f(ww.z)
         + xp[6]*lo_f(ww.w) + xp[7]*hi_f(ww.w);
    }
  }
  float s = a, q = a*a;
  for (int m = 32; m >= 1; m >>= 1){ s += __shfl_xor(s,m); q += __shfl_xor(q,m); }
  if ((tid & 63) == 0){ red[tid>>6] = s; red[4+(tid>>6)] = q; }
  __syncthreads();
  s = red[0]+red[1]+red[2]+red[3]; q = red[4]+red[5]+red[6]+red[7];
  float mean = s*(1.f/HH), var = q*(1.f/HH) - mean*mean, rstd = rsqrtf(var + 1e-5f);
  float h = fmaxf((a-mean)*rstd*g1g[tid] + be1g[tid], 0.f);
  hr[tid] = h;
  __syncthreads();
  float a2[3];
  #pragma unroll
  for (int u = 0; u < 3; ++u){
    int c = tid + 256*u;
    float t = b2g[c];
    const uint4* wr = (const uint4*)(w2T + (size_t)c*256);
    #pragma unroll 4
    for (int kk = 0; kk < 32; ++kk){
      uint4 ww = wr[kk];
      const float* hp = &hr[kk*8];
      t += hp[0]*lo_f(ww.x) + hp[1]*hi_f(ww.x)
         + hp[2]*lo_f(ww.y) + hp[3]*hi_f(ww.y)
         + hp[4]*lo_f(ww.z) + hp[5]*hi_f(ww.z)
         + hp[6]*lo_f(ww.w) + hp[7]*hi_f(ww.w);
    }
    a2[u] = t;
  }
  float s2 = a2[0]+a2[1]+a2[2], q2 = a2[0]*a2[0]+a2[1]*a2[1]+a2[2]*a2[2];
  for (int m = 32; m >= 1; m >>= 1){ s2 += __shfl_xor(s2,m); q2 += __shfl_xor(q2,m); }
  __syncthreads();
  if ((tid & 63) == 0){ red[tid>>6] = s2; red[4+(tid>>6)] = q2; }
  __syncthreads();
  s2 = red[0]+red[1]+red[2]+red[3]; q2 = red[4]+red[5]+red[6]+red[7];
  float mean2 = s2*(1.f/DD), rstd2 = rsqrtf(q2*(1.f/DD) - mean2*mean2 + 1e-5f);
  #pragma unroll
  for (int u = 0; u < 3; ++u){
    int c = tid + 256*u;
    comb[base + c] = (a2[u]-mean2)*rstd2*g2g[c] + be2g[c] + mg[base + c]*inv;
  }
}

// ================= gather + enhanced =================
__global__ void k_enhance(const float* __restrict__ feat, const int* __restrict__ lab,
                          const float* __restrict__ cntw, const float* __restrict__ comb,
                          float* __restrict__ enh, unsigned short* __restrict__ enhb)
{
  int idx = blockIdx.x * 256 + threadIdx.x;
  int c = idx % DD; int bn = idx / DD; int b = bn / NN;
  int l = lab[bn];
  float f = feat[idx];
  float cg = comb[(size_t)(b*SS + l)*DD + c];
  float cnt = cntw[b*SS + l];
  float e = (cnt >= 2.0f) ? (0.7f*f + 0.3f*cg) : f;
  enh[idx] = e;
  enhb[idx] = f_bits(e);
}

// ================= q/k/v projections via MFMA (16-row tiles, 432 blocks) =================
__global__ __launch_bounds__(256, 4) void k_qkv(
    const unsigned short* __restrict__ enhb, const unsigned short* __restrict__ geo,
    const short* __restrict__ wqT, const short* __restrict__ wkT, const short* __restrict__ wvT,
    const float* __restrict__ bq, const float* __restrict__ bk, const float* __restrict__ bv,
    unsigned short* __restrict__ qo, unsigned short* __restrict__ ko, unsigned short* __restrict__ vo)
{
  const int tid = threadIdx.x, blk = blockIdx.x;   // 432 = 3 mats * 48 rt * 3 ct
  const int m = blk / 144, rem = blk % 144;
  const int rt = rem / 3, ct = rem % 3;
  const int wave = tid >> 6, lane = tid & 63, quad = lane >> 4, l16 = lane & 15;
  const short* WT = (m==0)?wqT:(m==1)?wkT:wvT;
  const float* Bv = (m==0)?bq:(m==1)?bk:bv;
  unsigned short* Y = (m==0)?qo:(m==1)?ko:vo;
  const short* X = (const short*)((m==0)? enhb : geo);
  const float oscale = (m==0)? 0.10206207261596577f : 1.0f;
  const int row0 = rt*16;
  const int col0 = ct*256 + wave*64;

  f32x4 acc[4];
  #pragma unroll
  for (int cb=0;cb<4;++cb) acc[cb] = (f32x4){0.f,0.f,0.f,0.f};
  for (int ks = 0; ks < 24; ++ks){
    bf16x8 af = *(const bf16x8*)&X[(size_t)(row0 + l16)*DD + ks*32 + quad*8];
    #pragma unroll
    for (int cb=0;cb<4;++cb){
      bf16x8 bw = *(const bf16x8*)&WT[(size_t)(col0 + cb*16 + l16)*DD + ks*32 + quad*8];
      acc[cb] = __builtin_amdgcn_mfma_f32_16x16x32_bf16(af, bw, acc[cb], 0,0,0);
    }
  }
  #pragma unroll
  for (int cb=0;cb<4;++cb){
    int col = col0 + cb*16 + l16;
    float bb = Bv[col];
    #pragma unroll
    for (int r=0;r<4;++r){
      int row = row0 + quad*4 + r;
      Y[(size_t)row*DD + col] = f_bits((acc[cb][r] + bb)*oscale);
    }
  }
}

// ================= attention: split over jt halves (384 blocks) =================
__global__ __launch_bounds__(256) void k_attn_split(
    const unsigned short* __restrict__ qws, const unsigned short* __restrict__ kws,
    const unsigned short* __restrict__ vws, float* __restrict__ pws)
{
  __shared__ short kt[64*104];
  __shared__ short vt[64*104];
  __shared__ float st[32*66];
  __shared__ float lsum[32];
  const int tid = threadIdx.x;
  const int half = blockIdx.x / 192;
  const int inner = blockIdx.x % 192;
  const int b = inner / (NHH*12); int rem = inner % (NHH*12);
  const int h = rem / 12; const int qt = rem % 12; const int q0 = qt*32;
  const int sq = tid >> 3, jp = tid & 7;
  const int qp = tid >> 4, dp = tid & 15;
  unsigned qreg[48];
  {
    const unsigned* qr = (const unsigned*)(qws + (size_t)(b*NN + q0 + sq)*DD + h*DHH);
    #pragma unroll
    for (int d2 = 0; d2 < 48; ++d2) qreg[d2] = qr[d2];
  }
  if (tid < 32) lsum[tid] = 0.f;
  float Oacc[2][6];
  #pragma unroll
  for (int a = 0; a < 2; ++a)
    #pragma unroll
    for (int m = 0; m < 6; ++m) Oacc[a][m] = 0.f;

  for (int jt = half*3; jt < half*3 + 3; ++jt){
    const int j0 = jt * 64;
    __syncthreads();
    for (int x = tid; x < 64*48; x += 256){
      int jl = x / 48, du = x % 48;
      size_t rowoff = (size_t)(b*NN + j0 + jl)*DD + h*DHH;
      ((unsigned*)&kt[jl*104])[du] = ((const unsigned*)(kws + rowoff))[du];
      ((unsigned*)&vt[jl*104])[du] = ((const unsigned*)(vws + rowoff))[du];
    }
    __syncthreads();
    float lpart = 0.f;
    #pragma unroll
    for (int jj = 0; jj < 8; ++jj){
      int j = jp*8 + jj;
      const uint4* kr4 = (const uint4*)&kt[j*104];
      float s = 0.f;
      #pragma unroll
      for (int d4 = 0; d4 < 12; ++d4){
        uint4 kk = kr4[d4];
        unsigned q0r = qreg[4*d4], q1r = qreg[4*d4+1], q2r = qreg[4*d4+2], q3r = qreg[4*d4+3];
        s += lo_f(kk.x)*lo_f(q0r) + hi_f(kk.x)*hi_f(q0r);
        s += lo_f(kk.y)*lo_f(q1r) + hi_f(kk.y)*hi_f(q1r);
        s += lo_f(kk.z)*lo_f(q2r) + hi_f(kk.z)*hi_f(q2r);
        s += lo_f(kk.w)*lo_f(q3r) + hi_f(kk.w)*hi_f(q3r);
      }
      float p = __expf(s);
      st[sq*66 + j] = p;
      lpart += p;
    }
    lpart += __shfl_xor(lpart,1);
    lpart += __shfl_xor(lpart,2);
    lpart += __shfl_xor(lpart,4);
    if (jp == 0) lsum[sq] += lpart;
    __syncthreads();
    #pragma unroll 4
    for (int j = 0; j < 64; ++j){
      float p0 = st[(2*qp)*66 + j];
      float p1 = st[(2*qp+1)*66 + j];
      const unsigned* vr = (const unsigned*)&vt[j*104 + dp*6];
      #pragma unroll
      for (int m = 0; m < 3; ++m){
        unsigned vv = vr[m];
        float v0 = lo_f(vv), v1 = hi_f(vv);
        Oacc[0][2*m]   += p0*v0; Oacc[0][2*m+1] += p0*v1;
        Oacc[1][2*m]   += p1*v0; Oacc[1][2*m+1] += p1*v1;
      }
    }
  }
  __syncthreads();
  float* pb = pws + ((size_t)inner*2 + half)*3104;
  #pragma unroll
  for (int m = 0; m < 6; ++m){
    pb[(2*qp)*96 + dp*6 + m]   = Oacc[0][m];
    pb[(2*qp+1)*96 + dp*6 + m] = Oacc[1][m];
  }
  if (tid < 32) pb[3072 + tid] = lsum[tid];
}

// ================= attention finalize =================
__global__ __launch_bounds__(256) void k_attnfin(
    const float* __restrict__ pws, unsigned short* __restrict__ ows)
{
  __shared__ float ls[32];
  const int tid = threadIdx.x, inner = blockIdx.x;
  const int b = inner / (NHH*12); int rem = inner % (NHH*12);
  const int h = rem / 12; const int qt = rem % 12; const int q0 = qt*32;
  const float* p0 = pws + (size_t)inner*2*3104;
  const float* p1 = p0 + 3104;
  if (tid < 32) ls[tid] = 1.f / (p0[3072+tid] + p1[3072+tid]);
  __syncthreads();
  #pragma unroll
  for (int u = 0; u < 12; ++u){
    int e = tid + u*256;
    int q = e / 96, d = e % 96;
    float o = (p0[e] + p1[e]) * ls[q];
    ows[(size_t)(b*NN + q0 + q)*DD + h*DHH + d] = f_bits(o);
  }
}

// ================= attention fallback (single-pass) =================
__global__ __launch_bounds__(256) void k_attn_full(
    const unsigned short* __restrict__ qws, const unsigned short* __restrict__ kws,
    const unsigned short* __restrict__ vws, unsigned short* __restrict__ ows)
{
  __shared__ short kt[64*104];
  __shared__ short vt[64*104];
  __shared__ float st[32*66];
  __shared__ float lsum[32];
  const int tid = threadIdx.x;
  const int blk = blockIdx.x;
  const int b = blk / (NHH*12); int rem = blk % (NHH*12);
  const int h = rem / 12; const int qt = rem % 12; const int q0 = qt*32;
  const int sq = tid >> 3, jp = tid & 7;
  const int qp = tid >> 4, dp = tid & 15;
  unsigned qreg[48];
  {
    const unsigned* qr = (const unsigned*)(qws + (size_t)(b*NN + q0 + sq)*DD + h*DHH);
    #pragma unroll
    for (int d2 = 0; d2 < 48; ++d2) qreg[d2] = qr[d2];
  }
  if (tid < 32) lsum[tid] = 0.f;
  float Oacc[2][6];
  #pragma unroll
  for (int a = 0; a < 2; ++a)
    #pragma unroll
    for (int m = 0; m < 6; ++m) Oacc[a][m] = 0.f;
  for (int jt = 0; jt < 6; ++jt){
    const int j0 = jt * 64;
    __syncthreads();
    for (int x = tid; x < 64*48; x += 256){
      int jl = x / 48, du = x % 48;
      size_t rowoff = (size_t)(b*NN + j0 + jl)*DD + h*DHH;
      ((unsigned*)&kt[jl*104])[du] = ((const unsigned*)(kws + rowoff))[du];
      ((unsigned*)&vt[jl*104])[du] = ((const unsigned*)(vws + rowoff))[du];
    }
    __syncthreads();
    float lpart = 0.f;
    #pragma unroll
    for (int jj = 0; jj < 8; ++jj){
      int j = jp*8 + jj;
      const uint4* kr4 = (const uint4*)&kt[j*104];
      float s = 0.f;
      #pragma unroll
      for (int d4 = 0; d4 < 12; ++d4){
        uint4 kk = kr4[d4];
        unsigned q0r = qreg[4*d4], q1r = qreg[4*d4+1], q2r = qreg[4*d4+2], q3r = qreg[4*d4+3];
        s += lo_f(kk.x)*lo_f(q0r) + hi_f(kk.x)*hi_f(q0r);
        s += lo_f(kk.y)*lo_f(q1r) + hi_f(kk.y)*hi_f(q1r);
        s += lo_f(kk.z)*lo_f(q2r) + hi_f(kk.z)*hi_f(q2r);
        s += lo_f(kk.w)*lo_f(q3r) + hi_f(kk.w)*hi_f(q3r);
      }
      float p = __expf(s);
      st[sq*66 + j] = p;
      lpart += p;
    }
    lpart += __shfl_xor(lpart,1);
    lpart += __shfl_xor(lpart,2);
    lpart += __shfl_xor(lpart,4);
    if (jp == 0) lsum[sq] += lpart;
    __syncthreads();
    #pragma unroll 4
    for (int j = 0; j < 64; ++j){
      float p0 = st[(2*qp)*66 + j];
      float p1 = st[(2*qp+1)*66 + j];
      const unsigned* vr = (const unsigned*)&vt[j*104 + dp*6];
      #pragma unroll
      for (int m = 0; m < 3; ++m){
        unsigned vv = vr[m];
        float v0 = lo_f(vv), v1 = hi_f(vv);
        Oacc[0][2*m]   += p0*v0; Oacc[0][2*m+1] += p0*v1;
        Oacc[1][2*m]   += p1*v0; Oacc[1][2*m+1] += p1*v1;
      }
    }
  }
  __syncthreads();
  float l0 = 1.f / lsum[2*qp], l1 = 1.f / lsum[2*qp+1];
  size_t ob = (size_t)(b*NN + q0)*DD + h*DHH + dp*6;
  #pragma unroll
  for (int m = 0; m < 6; ++m){
    ows[ob + (size_t)(2*qp)*DD + m]   = f_bits(Oacc[0][m]*l0);
    ows[ob + (size_t)(2*qp+1)*DD + m] = f_bits(Oacc[1][m]*l1);
  }
}

// ================= output projection via MFMA (16-row tiles, 144 blocks) =================
__global__ __launch_bounds__(256, 4) void k_out(
    const unsigned short* __restrict__ ows, const float* __restrict__ enh,
    const short* __restrict__ woT, const float* __restrict__ bo, float* __restrict__ out)
{
  const int tid = threadIdx.x, blk = blockIdx.x;   // 144 = 48 rt * 3 ct
  const int rt = blk / 3, ct = blk % 3;
  const int wave = tid >> 6, lane = tid & 63, quad = lane >> 4, l16 = lane & 15;
  const int row0 = rt*16;
  const int col0 = ct*256 + wave*64;
  f32x4 acc[4];
  #pragma unroll
  for (int cb=0;cb<4;++cb) acc[cb] = (f32x4){0.f,0.f,0.f,0.f};
  for (int ks = 0; ks < 24; ++ks){
    bf16x8 af = *(const bf16x8*)&((const short*)ows)[(size_t)(row0 + l16)*DD + ks*32 + quad*8];
    #pragma unroll
    for (int cb=0;cb<4;++cb){
      bf16x8 bw = *(const bf16x8*)&woT[(size_t)(col0 + cb*16 + l16)*DD + ks*32 + quad*8];
      acc[cb] = __builtin_amdgcn_mfma_f32_16x16x32_bf16(af, bw, acc[cb], 0,0,0);
    }
  }
  #pragma unroll
  for (int cb=0;cb<4;++cb){
    int col = col0 + cb*16 + l16;
    float bb = bo[col];
    #pragma unroll
    for (int r=0;r<4;++r){
      size_t idx = (size_t)(row0 + quad*4 + r)*DD + col;
      out[idx] = enh[idx] + 0.5f*(acc[cb][r] + bb);
    }
  }
}

extern "C" void kernel_launch(void* const* d_in, const int* in_sizes, int n_in,
                              void* d_out, int out_size, void* d_ws, size_t ws_size,
                              hipStream_t stream) {
  const float* coord = (const float*)d_in[0];
  const float* feat  = (const float*)d_in[1];
  const int*   lab   = (const int*)d_in[2];
  const float* ge_w1 = (const float*)d_in[3];
  const float* ge_b1 = (const float*)d_in[4];
  const float* ge_g1 = (const float*)d_in[5];
  const float* ge_be1= (const float*)d_in[6];
  const float* ge_w2 = (const float*)d_in[7];
  const float* ge_b2 = (const float*)d_in[8];
  const float* ge_g2 = (const float*)d_in[9];
  const float* ge_be2= (const float*)d_in[10];
  const float* ag_w1 = (const float*)d_in[11];
  const float* ag_b1 = (const float*)d_in[12];
  const float* ag_g1 = (const float*)d_in[13];
  const float* ag_be1= (const float*)d_in[14];
  const float* ag_w2 = (const float*)d_in[15];
  const float* ag_b2 = (const float*)d_in[16];
  const float* ag_g2 = (const float*)d_in[17];
  const float* ag_be2= (const float*)d_in[18];
  const float* wq = (const float*)d_in[19];
  const float* bq = (const float*)d_in[20];
  const float* wk = (const float*)d_in[21];
  const float* bk = (const float*)d_in[22];
  const float* wv = (const float*)d_in[23];
  const float* bv = (const float*)d_in[24];
  const float* wo = (const float*)d_in[25];
  const float* bo = (const float*)d_in[26];

  // Workspace base 16,692,480 B (+4,767,744 pws if available -> 21,460,224).
  char* w = (char*)d_ws;
  unsigned short* geo_bf = (unsigned short*)(w);              // 1,179,648  [ow overlay]
  float*          enh_f  = (float*)(w + 1179648);             // 2,359,296
  unsigned short* enh_bf = (unsigned short*)(w + 3538944);    // 1,179,648
  unsigned short* qw_bf  = (unsigned short*)(w + 4718592);    // 1,179,648
  unsigned short* kw_bf  = (unsigned short*)(w + 5898240);    // 1,179,648
  unsigned short* vw_bf  = (unsigned short*)(w + 7077888);    // 1,179,648
  float*          gv     = (float*)(w + 8257536);             //   798,720
  float*          mf     = (float*)(w + 9056256);             //   393,216
  float*          mg     = (float*)(w + 9449472);             //   393,216
  float*          cntw   = (float*)(w + 9842688);             //       512
  float*          comb   = (float*)(w + 9843200);             //   393,216
  short*          w2T    = (short*)(w + 10236416);            //   393,216
  short*          w2r    = (short*)(w + 10629632);            //   393,216
  short*          w1t    = (short*)(w + 11022848);            //    16,384
  short*          Gm     = (short*)(w + 11039232);            //   147,456
  float*          g1s    = (float*)(w + 11186688);            //       512
  float*          gscal  = (float*)(w + 11187200);            //       256
  short*          wqT    = (short*)(w + 11187456);            // 1,179,648
  short*          wkT    = (short*)(w + 12367104);            // 1,179,648
  short*          wvT    = (short*)(w + 13546752);            // 1,179,648
  short*          woT    = (short*)(w + 14726400);            // 1,179,648
  short*          agw1T  = (short*)(w + 15906048);            //   393,216
  short*          agw2T  = (short*)(w + 16299264);            //   393,216
  float*          pws    = (float*)(w + 16692480);            // 4,767,744 (optional)
  unsigned short* ow_bf  = geo_bf;
  const bool split_attn = (ws_size >= 21460224);

  hipLaunchKernelGGL(k_prep,    dim3(3069),  dim3(256), 0, stream,
                     ge_w2, ge_w1, wq, wk, wv, wo, ag_w1, ag_w2,
                     gv, w2T, w2r, wqT, wkT, wvT, woT, w1t, agw1T, agw2T);
  hipLaunchKernelGGL(k_gprep,   dim3(66),    dim3(256), 0, stream,
                     w2r, ge_b2, w1t, ge_b1, Gm, gscal, g1s);
  hipLaunchKernelGGL(k_geo,     dim3(4608),  dim3(256), 0, stream,
                     coord, w1t, ge_b1, ge_g1, ge_be1, Gm, gscal, g1s, gv);
  hipLaunchKernelGGL(k_geoscat, dim3(768),   dim3(256), 0, stream,
                     gv, w2r, ge_b2, ge_g2, ge_be2, geo_bf, lab, feat, mf, mg, cntw);
  hipLaunchKernelGGL(k_agg,     dim3(128),   dim3(256), 0, stream,
                     mf, mg, cntw, agw1T, ag_b1, ag_g1, ag_be1, agw2T, ag_b2, ag_g2, ag_be2, comb);
  hipLaunchKernelGGL(k_enhance, dim3(2304),  dim3(256), 0, stream,
                     feat, lab, cntw, comb, enh_f, enh_bf);
  hipLaunchKernelGGL(k_qkv,     dim3(432),   dim3(256), 0, stream,
                     enh_bf, geo_bf, wqT, wkT, wvT, bq, bk, bv, qw_bf, kw_bf, vw_bf);
  if (split_attn){
    hipLaunchKernelGGL(k_attn_split, dim3(384), dim3(256), 0, stream,
                       qw_bf, kw_bf, vw_bf, pws);
    hipLaunchKernelGGL(k_attnfin,    dim3(192), dim3(256), 0, stream,
                       pws, ow_bf);
  } else {
    hipLaunchKernelGGL(k_attn_full,  dim3(192), dim3(256), 0, stream,
                       qw_bf, kw_bf, vw_bf, ow_bf);
  }
  hipLaunchKernelGGL(k_out,     dim3(144),   dim3(256), 0, stream,
                     ow_bf, enh_f, woT, bo, (float*)d_out);
}